// Round 4
// baseline (15189.597 us; speedup 1.0000x reference)
//
#include <hip/hip_runtime.h>
#include <hip/hip_bf16.h>

// Problem constants
#define B_   4096
#define S_   64
#define D_   9
#define H_   128
#define HZ_  32
#define DT_  0.1f

// Workspace layout (float offsets, f32 region)
#define OFF_WET    0          // 16384  : W_e^T   (256 x 64)
#define OFF_VET    16384      // 4096   : V_e^T   (64 x 64)
#define OFF_WENCT  20480      // 70144  : W_enc^T (137 x 512)
#define OFF_BENC   90624      // 512
#define OFF_WDT    91136      // 32768  : (legacy, unused)
#define OFF_WDECT  123904     // 135680 : (legacy, unused)
#define OFF_BDEC   259584     // 512
#define OFF_WOUTT  260096     // 768    : W_out^T (256 x 3), cat=[d|ctx]
#define OFF_VDT    260864     // 16384  : V_d^T [i][k]
#define OFF_DECD   277248     // 524288 : final encoder h
#define OFF_DECC   801536     // 524288 : final encoder c
#define F32_TOTAL  1325824
#define PREP_N     277248

// bf16 (ushort) region after f32 region:
//   EH     : B*S*H = 33554432
//   AET    : B*16*64*8 = 33554432
//   WdTm   : 8ks*8nt*64*8 = 32768        (W_d MFMA-B order, K=[d;c])
//   WdecTm : 8is*4q*9ks*64*8 = 147456    (W_dec MFMA-B, gate-permuted cols)

#define ENC_M 8
#define DEC_M 16

typedef __bf16 bf16x8 __attribute__((ext_vector_type(8)));
typedef float  f32x4  __attribute__((ext_vector_type(4)));
typedef unsigned int u32x4_t __attribute__((ext_vector_type(4)));

__device__ __forceinline__ float fast_tanh(float x) {
    float e = __expf(2.0f * x);
    return 1.0f - __fdividef(2.0f, e + 1.0f);
}
__device__ __forceinline__ float sigf(float x) {
    return __fdividef(1.0f, 1.0f + __expf(-x));
}
__device__ __forceinline__ float wred_sum(float v) {
    #pragma unroll
    for (int off = 32; off; off >>= 1) v += __shfl_xor(v, off, 64);
    return v;
}
__device__ __forceinline__ float bf_lo(unsigned int u) { return __uint_as_float(u << 16); }
__device__ __forceinline__ float bf_hi(unsigned int u) { return __uint_as_float(u & 0xffff0000u); }
__device__ __forceinline__ unsigned short f2bfu(float f) {
    __hip_bfloat16 b = __float2bfloat16(f);
    return *(unsigned short*)&b;
}
__device__ __forceinline__ unsigned int pack_bf(float lo, float hi) {
    return (unsigned int)f2bfu(lo) | ((unsigned int)f2bfu(hi) << 16);
}
__device__ __forceinline__ u32x4_t ntload4(const unsigned short* p) {
    return __builtin_nontemporal_load((const u32x4_t*)p);
}

// ---------------------------------------------------------------- prep (f32 tables)
__global__ void prep_kernel(const float* __restrict__ Wih_e, const float* __restrict__ Whh_e,
    const float* __restrict__ bih_e, const float* __restrict__ bhh_e,
    const float* __restrict__ W_e, const float* __restrict__ V_e,
    const float* __restrict__ W_d, const float* __restrict__ V_d,
    const float* __restrict__ Wih_d, const float* __restrict__ Whh_d,
    const float* __restrict__ bih_d, const float* __restrict__ bhh_d,
    const float* __restrict__ W_out, float* __restrict__ ws) {
  for (int idx = blockIdx.x * blockDim.x + threadIdx.x; idx < PREP_N;
       idx += gridDim.x * blockDim.x) {
    int i = idx;
    if (i < 16384) { int k = i >> 6, s = i & 63; ws[OFF_WET + i] = W_e[s * 256 + k]; continue; }
    i -= 16384;
    if (i < 4096) { int s = i >> 6, t = i & 63; ws[OFF_VET + i] = V_e[t * 64 + s]; continue; }
    i -= 4096;
    if (i < 70144) {
      int k = i / 512, g = i & 511;
      ws[OFF_WENCT + i] = (k < 128) ? Whh_e[g * 128 + k] : Wih_e[g * 9 + (k - 128)];
      continue;
    }
    i -= 70144;
    if (i < 512) { ws[OFF_BENC + i] = bih_e[i] + bhh_e[i]; continue; }
    i -= 512;
    if (i < 32768) { int k = i >> 7, j = i & 127; ws[OFF_WDT + i] = W_d[j * 256 + k]; continue; }
    i -= 32768;
    if (i < 135680) {
      int k = i / 512, g = i & 511; float v;
      if (k < 128)      v = Whh_d[g * 128 + k];
      else if (k < 256) v = Wih_d[g * 137 + 9 + (k - 128)];
      else              v = Wih_d[g * 137 + (k - 256)];
      ws[OFF_WDECT + i] = v; continue;
    }
    i -= 135680;
    if (i < 512) { ws[OFF_BDEC + i] = bih_d[i] + bhh_d[i]; continue; }
    i -= 512;
    if (i < 768) { int k = i / 3, j = i % 3; ws[OFF_WOUTT + i] = W_out[j * 256 + k]; continue; }
    i -= 768;
    { int ii = i >> 7, j = i & 127; ws[OFF_VDT + i] = V_d[j * 128 + ii]; }
  }
}

// ---------------------------------------------------------------- prep (MFMA B-fragment bf16 weights)
// WdTm  : tiles (ks 0..7, nt 0..7); lane l, j: k=ks*32+(l>>4)*8+j, n=nt*16+(l&15); val=W_d[n][k]
// WdecTm: tiles (is 0..7, q 0..3, ks 0..8); k=ks*32+(l>>4)*8+j over [d|ctx|phys|0];
//         output col = gate q, i = is*16+(l&15)  -> W_dec row g = q*128+i
__global__ void prep_mfma_kernel(const float* __restrict__ W_d,
    const float* __restrict__ Wih_d, const float* __restrict__ Whh_d,
    unsigned short* __restrict__ WdTm, unsigned short* __restrict__ WdecTm) {
  int idx = blockIdx.x * blockDim.x + threadIdx.x;
  if (idx < 32768) {
    int j = idx & 7, l = (idx >> 3) & 63, t = idx >> 9;
    int nt = t & 7, ks = t >> 3;
    int k = ks * 32 + (l >> 4) * 8 + j;
    int n = nt * 16 + (l & 15);
    WdTm[idx] = f2bfu(W_d[n * 256 + k]);
    return;
  }
  int i2 = idx - 32768;
  if (i2 < 147456) {
    int j = i2 & 7, l = (i2 >> 3) & 63, t = i2 >> 9;   // t in [0,288)
    int ks = t % 9, tile = t / 9;
    int q = tile & 3, is = tile >> 2;
    int k = ks * 32 + (l >> 4) * 8 + j;
    int g = q * 128 + is * 16 + (l & 15);
    float v;
    if (k < 128)      v = Whh_d[g * 128 + k];
    else if (k < 256) v = Wih_d[g * 137 + 9 + (k - 128)];
    else if (k < 265) v = Wih_d[g * 137 + (k - 256)];
    else              v = 0.f;
    WdecTm[i2] = f2bfu(v);
  }
}

// ---------------------------------------------------------------- encoder (unchanged R1 form)
__global__ __launch_bounds__(256, 2) void encoder_kernel(
    const float* __restrict__ x_in, const float* __restrict__ ws,
    const float* __restrict__ v_e_g, __hip_bfloat16* __restrict__ EH,
    float* __restrict__ decd, float* __restrict__ decc) {
  __shared__ float hc[ENC_M][272];
  __shared__ float xb[ENC_M][576];
  __shared__ float ai[ENC_M][576];
  __shared__ float ah[ENC_M][64];
  __shared__ float gl[ENC_M][512];
  __shared__ float ve[64];

  const int tid = threadIdx.x;
  const int b0 = blockIdx.x * ENC_M;
  const int lane = tid & 63, wv = tid >> 6;

  for (int i = tid; i < ENC_M * 576; i += 256) {
    int m = i / 576, r = i % 576;
    xb[m][r] = x_in[(size_t)(b0 + m) * 576 + r];
  }
  if (tid < 64) ve[tid] = v_e_g[tid];
  for (int i = tid; i < ENC_M * 256; i += 256) { int m = i >> 8, r = i & 255; hc[m][r] = 0.f; }
  __syncthreads();

  const float* __restrict__ VeT = ws + OFF_VET;
  for (int i = tid; i < ENC_M * 576; i += 256) {
    int t = i & 63, dd = (i >> 6) % 9, m = i / 576;
    float acc = 0.f;
    for (int s = 0; s < 64; ++s) acc += xb[m][s * 9 + dd] * VeT[s * 64 + t];
    ai[m][dd * 64 + t] = acc;
  }
  __syncthreads();

  const float* __restrict__ WeT   = ws + OFF_WET;
  const float* __restrict__ WencT = ws + OFF_WENCT;
  const float* __restrict__ benc  = ws + OFF_BENC;

  for (int t = 0; t < S_; ++t) {
    {
      const int s = lane, m0 = wv, m1 = wv + 4;
      float a0 = 0.f, a1 = 0.f;
      for (int k = 0; k < 256; k += 4) {
        float w0 = WeT[(k + 0) * 64 + s], w1 = WeT[(k + 1) * 64 + s];
        float w2 = WeT[(k + 2) * 64 + s], w3 = WeT[(k + 3) * 64 + s];
        const float4 h0 = *(const float4*)&hc[m0][k];
        const float4 h1 = *(const float4*)&hc[m1][k];
        a0 += w0 * h0.x + w1 * h0.y + w2 * h0.z + w3 * h0.w;
        a1 += w0 * h1.x + w1 * h1.y + w2 * h1.z + w3 * h1.w;
      }
      ah[m0][s] = a0; ah[m1][s] = a1;
    }
    __syncthreads();
    #pragma unroll
    for (int half = 0; half < 2; ++half) {
      const int mi = wv + half * 4;
      float e_reg = -1e30f;
      for (int dd = 0; dd < 9; ++dd) {
        float a  = ah[mi][lane] + ai[mi][dd * 64 + lane];
        float tv = fast_tanh(a) * ve[lane];
        float e_dd = wred_sum(tv);
        if (lane == dd) e_reg = e_dd;
      }
      float mval = e_reg;
      #pragma unroll
      for (int off = 8; off; off >>= 1) mval = fmaxf(mval, __shfl_xor(mval, off, 64));
      float ex = (lane < 9) ? __expf(e_reg - mval) : 0.f;
      float ssum = ex;
      #pragma unroll
      for (int off = 8; off; off >>= 1) ssum += __shfl_xor(ssum, off, 64);
      if (lane < 9) hc[mi][256 + lane] = __fdividef(ex, ssum) * xb[mi][t * 9 + lane];
    }
    __syncthreads();
    {
      const int g0 = tid, g1 = tid + 256;
      float acc0[ENC_M], acc1[ENC_M];
      const float bb0 = benc[g0], bb1 = benc[g1];
      #pragma unroll
      for (int m = 0; m < ENC_M; ++m) { acc0[m] = bb0; acc1[m] = bb1; }
      for (int k = 0; k < 128; k += 4) {
        float w00 = WencT[(k + 0) * 512 + g0], w01 = WencT[(k + 0) * 512 + g1];
        float w10 = WencT[(k + 1) * 512 + g0], w11 = WencT[(k + 1) * 512 + g1];
        float w20 = WencT[(k + 2) * 512 + g0], w21 = WencT[(k + 2) * 512 + g1];
        float w30 = WencT[(k + 3) * 512 + g0], w31 = WencT[(k + 3) * 512 + g1];
        #pragma unroll
        for (int m = 0; m < ENC_M; ++m) {
          const float4 hv = *(const float4*)&hc[m][k];
          acc0[m] += w00 * hv.x + w10 * hv.y + w20 * hv.z + w30 * hv.w;
          acc1[m] += w01 * hv.x + w11 * hv.y + w21 * hv.z + w31 * hv.w;
        }
      }
      #pragma unroll
      for (int k = 0; k < 9; ++k) {
        float w0 = WencT[(128 + k) * 512 + g0], w1 = WencT[(128 + k) * 512 + g1];
        #pragma unroll
        for (int m = 0; m < ENC_M; ++m) {
          float xv = hc[m][256 + k];
          acc0[m] += w0 * xv; acc1[m] += w1 * xv;
        }
      }
      #pragma unroll
      for (int m = 0; m < ENC_M; ++m) { gl[m][g0] = acc0[m]; gl[m][g1] = acc1[m]; }
    }
    __syncthreads();
    #pragma unroll
    for (int q = 0; q < 4; ++q) {
      int flat = tid + q * 256;
      int m = flat >> 7, i = flat & 127;
      float gi = gl[m][i], gf = gl[m][128 + i], gg = gl[m][256 + i], go = gl[m][384 + i];
      float co = hc[m][128 + i];
      float cn = sigf(gf) * co + sigf(gi) * fast_tanh(gg);
      float hn = sigf(go) * fast_tanh(cn);
      hc[m][i] = hn; hc[m][128 + i] = cn;
      EH[((size_t)(b0 + m) * S_ + t) * H_ + i] = __float2bfloat16(hn);
    }
    __syncthreads();
  }
  #pragma unroll
  for (int q = 0; q < 4; ++q) {
    int flat = tid + q * 256;
    int m = flat >> 7, i = flat & 127;
    decd[(size_t)(b0 + m) * H_ + i] = hc[m][i];
    decc[(size_t)(b0 + m) * H_ + i] = hc[m][128 + i];
  }
}

// ---------------------------------------------------------------- attn_encoder^T (k-packed)
__global__ __launch_bounds__(256, 4) void attnenc_t_kernel(const float* __restrict__ ws,
    const __hip_bfloat16* __restrict__ EH, unsigned short* __restrict__ AET) {
  __shared__ float EHsT[128 * 65];
  const int tid = threadIdx.x;
  const int b = blockIdx.x;
  const int s = tid & 63, kq = tid >> 6;

  for (int flat = tid; flat < 8192; flat += 256) {
    int ss = flat >> 7, ii = flat & 127;
    EHsT[ii * 65 + ss] = __bfloat162float(EH[(size_t)b * 8192 + flat]);
  }
  __syncthreads();

  const float* __restrict__ VdT = ws + OFF_VDT;
  float4 acc[8];
  #pragma unroll
  for (int g = 0; g < 8; ++g) acc[g] = make_float4(0.f, 0.f, 0.f, 0.f);
  for (int i = 0; i < 128; ++i) {
    float e = EHsT[i * 65 + s];
    const float4* w4 = (const float4*)(VdT + i * 128 + kq * 32);
    #pragma unroll
    for (int g = 0; g < 8; ++g) {
      float4 w = w4[g];
      acc[g].x += e * w.x; acc[g].y += e * w.y; acc[g].z += e * w.z; acc[g].w += e * w.w;
    }
  }
  unsigned short* outp = AET + (size_t)b * 8192;
  #pragma unroll
  for (int g = 0; g < 4; ++g) {
    float4 a0 = acc[2 * g], a1 = acc[2 * g + 1];
    uint4 pk;
    pk.x = pack_bf(a0.x, a0.y); pk.y = pack_bf(a0.z, a0.w);
    pk.z = pack_bf(a1.x, a1.y); pk.w = pack_bf(a1.z, a1.w);
    *(uint4*)(outp + (size_t)(kq * 4 + g) * 512 + s * 8) = pk;
  }
}

// ---------------------------------------------------------------- decoder
// DEC_M=16, 256 threads (4 waves). Per step, 3 barriers.
// Wave w owns: phase A n-tiles {2w,2w+1}; phases B/C batches {4w..4w+3};
// phase D/E i-slices {w, w+4} (all 16 batches, all 4 gates, in-register LSTM).
__global__ __launch_bounds__(256, 4) void decoder_kernel(
    const float* __restrict__ x_in, const float* __restrict__ ws,
    const __hip_bfloat16* __restrict__ EH, const unsigned short* __restrict__ AET,
    const unsigned short* __restrict__ WdTm, const unsigned short* __restrict__ WdecTm,
    const float* __restrict__ v_d_g, const float* __restrict__ b_out_g,
    const float* __restrict__ smean_g, const float* __restrict__ sstd_g,
    const float* __restrict__ pmean_g, float* __restrict__ out) {
  __shared__ unsigned short gA[16 * 296];  // bf16 [d 0..127|ctx 128..255|phys 256..264|pad..287]
  __shared__ unsigned short cA[16 * 136];  // bf16 c
  __shared__ float  cF[16 * 132];          // f32 c (stride 132 to spread banks)
  __shared__ unsigned short ad_s[16 * 136];// bf16 attn_dec (stride 136)
  __shared__ float  beta_s[16 * 64];
  __shared__ float  wout_c[384];           // ctx half of W_out^T
  __shared__ float  vd[128];
  __shared__ float  pd[16 * 3 * 8];        // d-part out partials [m][jj][is]
  __shared__ float  pc[48];                // ctx-part out partials [m][jj]
  __shared__ float  pvs[16][12];
  __shared__ float  cons[12];

  const int tid = threadIdx.x;
  const int b0 = blockIdx.x * DEC_M;
  const int l = tid & 63, w = tid >> 6;       // 4 waves
  const int quad = l >> 4, l15 = l & 15;

  const float* __restrict__ decd = ws + OFF_DECD;
  const float* __restrict__ decc = ws + OFF_DECC;

  // per-lane constant preloads (valid all steps)
  float bb[2][4], wd[2][3];
  #pragma unroll
  for (int t = 0; t < 2; ++t) {
    int i = (w + 4 * t) * 16 + l15;
    #pragma unroll
    for (int q = 0; q < 4; ++q) bb[t][q] = ws[OFF_BDEC + q * 128 + i];
    #pragma unroll
    for (int jj = 0; jj < 3; ++jj) wd[t][jj] = ws[OFF_WOUTT + i * 3 + jj];
  }

  for (int flat = tid; flat < 16 * 128; flat += 256) {
    int m = flat >> 7, i = flat & 127;
    float dv = decd[(size_t)(b0 + m) * H_ + i];
    float cv = decc[(size_t)(b0 + m) * H_ + i];
    gA[m * 296 + i] = f2bfu(dv);
    cA[m * 136 + i] = f2bfu(cv);
    cF[m * 132 + i] = cv;
  }
  for (int flat = tid; flat < 16 * 40; flat += 256) {
    int m = flat / 40, r = flat % 40;
    gA[m * 296 + 256 + r] = 0;
  }
  for (int i = tid; i < 384; i += 256) wout_c[i] = ws[OFF_WOUTT + 384 + i];
  if (tid < 128) vd[tid] = v_d_g[tid];
  if (tid < 3) { cons[tid] = smean_g[tid]; cons[3 + tid] = sstd_g[tid]; cons[6 + tid] = pmean_g[tid]; }
  __syncthreads();
  if (tid < 48) {
    int m = tid / 3, jj = tid % 3;
    const float* xi = x_in + (size_t)(b0 + m) * 576;
    float v  = xi[63 * 9 + 3 + jj] * cons[3 + jj] + cons[jj];
    float pv = xi[62 * 9 + 3 + jj] * cons[3 + jj] + cons[jj];
    pvs[m][jj]     = xi[63 * 9 + jj] + cons[6 + jj];
    pvs[m][3 + jj] = v;
    pvs[m][6 + jj] = (v - pv) / DT_;
  }
  __syncthreads();

  for (int hz = 0; hz < HZ_; ++hz) {
    // ---- A: ad = [d;c] @ W_d^T (MFMA). af_d kept for phase D (old d).
    u32x4_t af_d[4];
    {
      u32x4_t af_c[4];
      #pragma unroll
      for (int ks = 0; ks < 4; ++ks) {
        af_d[ks] = *(const u32x4_t*)&gA[l15 * 296 + ks * 32 + quad * 8];
        af_c[ks] = *(const u32x4_t*)&cA[l15 * 136 + ks * 32 + quad * 8];
      }
      #pragma unroll
      for (int t = 0; t < 2; ++t) {
        const int nt = 2 * w + t;
        f32x4 acc = {0.f, 0.f, 0.f, 0.f};
        #pragma unroll
        for (int ks = 0; ks < 8; ++ks) {
          u32x4_t au = (ks < 4) ? af_d[ks] : af_c[ks - 4];
          u32x4_t bu = *(const u32x4_t*)(WdTm + (size_t)((ks * 8 + nt) * 64 + l) * 8);
          acc = __builtin_amdgcn_mfma_f32_16x16x32_bf16(
              __builtin_bit_cast(bf16x8, au), __builtin_bit_cast(bf16x8, bu), acc, 0, 0, 0);
        }
        #pragma unroll
        for (int r = 0; r < 4; ++r)
          ad_s[(quad * 4 + r) * 136 + nt * 16 + l15] = f2bfu(acc[r]);
      }
    }
    __syncthreads();
    // ---- B: scores + softmax (lane = s). Wave w: batches 4w..4w+3.
    #pragma unroll
    for (int u = 0; u < 4; ++u) {
      const int mi = 4 * w + u;
      const unsigned short* aet = AET + (size_t)(b0 + mi) * 8192;
      float e_acc = 0.f;
      #pragma unroll
      for (int kb = 0; kb < 16; ++kb) {
        u32x4_t av = ntload4(aet + (size_t)kb * 512 + l * 8);
        u32x4_t ad8 = *(const u32x4_t*)&ad_s[mi * 136 + kb * 8];
        float4 v0 = *(const float4*)&vd[kb * 8];
        float4 v1 = *(const float4*)&vd[kb * 8 + 4];
        e_acc += fast_tanh(bf_lo(ad8[0]) + bf_lo(av[0])) * v0.x;
        e_acc += fast_tanh(bf_hi(ad8[0]) + bf_hi(av[0])) * v0.y;
        e_acc += fast_tanh(bf_lo(ad8[1]) + bf_lo(av[1])) * v0.z;
        e_acc += fast_tanh(bf_hi(ad8[1]) + bf_hi(av[1])) * v0.w;
        e_acc += fast_tanh(bf_lo(ad8[2]) + bf_lo(av[2])) * v1.x;
        e_acc += fast_tanh(bf_hi(ad8[2]) + bf_hi(av[2])) * v1.y;
        e_acc += fast_tanh(bf_lo(ad8[3]) + bf_lo(av[3])) * v1.z;
        e_acc += fast_tanh(bf_hi(ad8[3]) + bf_hi(av[3])) * v1.w;
      }
      float mx = e_acc;
      #pragma unroll
      for (int off = 32; off; off >>= 1) mx = fmaxf(mx, __shfl_xor(mx, off, 64));
      float ex = __expf(e_acc - mx);
      float ss = ex;
      #pragma unroll
      for (int off = 32; off; off >>= 1) ss += __shfl_xor(ss, off, 64);
      beta_s[mi * 64 + l] = __fdividef(ex, ss);
    }
    // ---- C (no barrier: same wave owns same batches): context + ctx·W_out partials
    #pragma unroll
    for (int u = 0; u < 4; ++u) {
      const int mi = 4 * w + u;
      const unsigned short* base = (const unsigned short*)(EH + (size_t)(b0 + mi) * 8192);
      float a[8];
      #pragma unroll
      for (int r = 0; r < 8; ++r) a[r] = 0.f;
      #pragma unroll
      for (int it = 0; it < 16; ++it) {
        int s = it * 4 + quad;
        u32x4_t ev = ntload4(base + (size_t)s * 128 + l15 * 8);
        float bt = beta_s[mi * 64 + s];
        a[0] += bt * bf_lo(ev[0]); a[1] += bt * bf_hi(ev[0]);
        a[2] += bt * bf_lo(ev[1]); a[3] += bt * bf_hi(ev[1]);
        a[4] += bt * bf_lo(ev[2]); a[5] += bt * bf_hi(ev[2]);
        a[6] += bt * bf_lo(ev[3]); a[7] += bt * bf_hi(ev[3]);
      }
      #pragma unroll
      for (int r = 0; r < 8; ++r) {
        a[r] += __shfl_xor(a[r], 16, 64);
        a[r] += __shfl_xor(a[r], 32, 64);
      }
      if (quad == 0) {
        u32x4_t pk;
        pk[0] = pack_bf(a[0], a[1]); pk[1] = pack_bf(a[2], a[3]);
        pk[2] = pack_bf(a[4], a[5]); pk[3] = pack_bf(a[6], a[7]);
        *(u32x4_t*)&gA[mi * 296 + 128 + l15 * 8] = pk;
      }
      float p0 = 0.f, p1 = 0.f, p2 = 0.f;
      #pragma unroll
      for (int r = 0; r < 8; ++r) {
        int ii = l15 * 8 + r;
        p0 += a[r] * wout_c[ii * 3 + 0];
        p1 += a[r] * wout_c[ii * 3 + 1];
        p2 += a[r] * wout_c[ii * 3 + 2];
      }
      #pragma unroll
      for (int off = 8; off; off >>= 1) {
        p0 += __shfl_xor(p0, off, 64);
        p1 += __shfl_xor(p1, off, 64);
        p2 += __shfl_xor(p2, off, 64);
      }
      if (l == 0) { pc[mi * 3 + 0] = p0; pc[mi * 3 + 1] = p1; pc[mi * 3 + 2] = p2; }
    }
    if (tid < 48) {
      int m = tid / 3, jj = tid % 3;
      gA[m * 296 + 256 + jj]     = f2bfu(pvs[m][jj] - cons[6 + jj]);
      gA[m * 296 + 256 + 3 + jj] = f2bfu((pvs[m][3 + jj] - cons[jj]) / cons[3 + jj]);
      gA[m * 296 + 256 + 6 + jj] = f2bfu(pvs[m][6 + jj] / cons[3 + jj]);
    }
    __syncthreads();
    // ---- D/E: gates (MFMA, gate-permuted) + in-register LSTM. Wave w: is in {w, w+4}.
    {
      u32x4_t af_cx[5];   // k 128..287 (ctx+phys); E never writes these ranges
      #pragma unroll
      for (int ks = 0; ks < 5; ++ks)
        af_cx[ks] = *(const u32x4_t*)&gA[l15 * 296 + (ks + 4) * 32 + quad * 8];
      #pragma unroll
      for (int t = 0; t < 2; ++t) {
        const int is = w + 4 * t;
        const int i  = is * 16 + l15;
        f32x4 g4[4];
        #pragma unroll
        for (int q = 0; q < 4; ++q) {
          f32x4 acc = {0.f, 0.f, 0.f, 0.f};
          #pragma unroll
          for (int ks = 0; ks < 9; ++ks) {
            u32x4_t au = (ks < 4) ? af_d[ks] : af_cx[ks - 4];
            u32x4_t bu = *(const u32x4_t*)(WdecTm + (size_t)(((is * 4 + q) * 9 + ks) * 64 + l) * 8);
            acc = __builtin_amdgcn_mfma_f32_16x16x32_bf16(
                __builtin_bit_cast(bf16x8, au), __builtin_bit_cast(bf16x8, bu), acc, 0, 0, 0);
          }
          g4[q] = acc;
        }
        float pr[4][3];
        #pragma unroll
        for (int r = 0; r < 4; ++r) {
          int m = quad * 4 + r;
          float gi = g4[0][r] + bb[t][0];
          float gf = g4[1][r] + bb[t][1];
          float gg = g4[2][r] + bb[t][2];
          float go = g4[3][r] + bb[t][3];
          float co = cF[m * 132 + i];
          float cn = sigf(gf) * co + sigf(gi) * fast_tanh(gg);
          float hn = sigf(go) * fast_tanh(cn);
          cF[m * 132 + i] = cn;
          cA[m * 136 + i] = f2bfu(cn);
          gA[m * 296 + i] = f2bfu(hn);
          pr[r][0] = hn * wd[t][0]; pr[r][1] = hn * wd[t][1]; pr[r][2] = hn * wd[t][2];
        }
        #pragma unroll
        for (int r = 0; r < 4; ++r)
          #pragma unroll
          for (int jj = 0; jj < 3; ++jj) {
            float v = pr[r][jj];
            #pragma unroll
            for (int off = 8; off; off >>= 1) v += __shfl_xor(v, off, 64);
            pr[r][jj] = v;
          }
        if (l15 == 0) {
          #pragma unroll
          for (int r = 0; r < 4; ++r)
            #pragma unroll
            for (int jj = 0; jj < 3; ++jj)
              pd[((quad * 4 + r) * 3 + jj) * 8 + is] = pr[r][jj];
        }
      }
    }
    __syncthreads();
    // ---- G: Verlet + output
    if (tid < 48) {
      int m = tid / 3, jj = tid % 3;
      float s = b_out_g[jj] + pc[m * 3 + jj];
      #pragma unroll
      for (int is = 0; is < 8; ++is) s += pd[(m * 3 + jj) * 8 + is];
      float pacc = s * cons[3 + jj];
      float pos = pvs[m][jj], vel = pvs[m][3 + jj], acc = pvs[m][6 + jj];
      float ppred = pos + vel * DT_ + 0.5f * acc * DT_ * DT_;
      float vnew  = vel + 0.5f * (acc + pacc) * DT_;
      size_t ob = ((size_t)(b0 + m) * HZ_ + hz) * 9;
      out[ob + jj] = ppred; out[ob + 3 + jj] = vnew; out[ob + 6 + jj] = pacc;
      pvs[m][jj] = ppred; pvs[m][3 + jj] = vnew; pvs[m][6 + jj] = pacc;
    }
    // no barrier: next A reads gA(d)/cA (post-D/E barrier covers); G touches only pvs/out/pd/pc
  }
}

// ---------------------------------------------------------------- launch
extern "C" void kernel_launch(void* const* d_in, const int* in_sizes, int n_in,
                              void* d_out, int out_size, void* d_ws, size_t ws_size,
                              hipStream_t stream) {
  (void)in_sizes; (void)n_in; (void)out_size; (void)ws_size;
  const float* x      = (const float*)d_in[0];
  const float* Wih_e  = (const float*)d_in[1];
  const float* Whh_e  = (const float*)d_in[2];
  const float* bih_e  = (const float*)d_in[3];
  const float* bhh_e  = (const float*)d_in[4];
  const float* W_e    = (const float*)d_in[5];
  const float* V_e    = (const float*)d_in[6];
  const float* v_e    = (const float*)d_in[7];
  const float* W_d    = (const float*)d_in[8];
  const float* V_d    = (const float*)d_in[9];
  const float* v_d    = (const float*)d_in[10];
  const float* Wih_d  = (const float*)d_in[11];
  const float* Whh_d  = (const float*)d_in[12];
  const float* bih_d  = (const float*)d_in[13];
  const float* bhh_d  = (const float*)d_in[14];
  const float* W_out  = (const float*)d_in[15];
  const float* b_out  = (const float*)d_in[16];
  const float* smean  = (const float*)d_in[17];
  const float* sstd   = (const float*)d_in[18];
  const float* pmean  = (const float*)d_in[19];

  float* ws = (float*)d_ws;
  __hip_bfloat16* EH  = (__hip_bfloat16*)(ws + F32_TOTAL);
  unsigned short* AET = (unsigned short*)(EH + (size_t)B_ * S_ * H_);
  unsigned short* WdTm   = AET + (size_t)B_ * S_ * H_;
  unsigned short* WdecTm = WdTm + 32768;
  float* out = (float*)d_out;

  prep_kernel<<<(PREP_N + 255) / 256, 256, 0, stream>>>(
      Wih_e, Whh_e, bih_e, bhh_e, W_e, V_e, W_d, V_d,
      Wih_d, Whh_d, bih_d, bhh_d, W_out, ws);
  prep_mfma_kernel<<<(32768 + 147456 + 255) / 256, 256, 0, stream>>>(
      W_d, Wih_d, Whh_d, WdTm, WdecTm);
  encoder_kernel<<<B_ / ENC_M, 256, 0, stream>>>(
      x, ws, v_e, EH, ws + OFF_DECD, ws + OFF_DECC);
  attnenc_t_kernel<<<B_, 256, 0, stream>>>(ws, EH, AET);
  decoder_kernel<<<B_ / DEC_M, 256, 0, stream>>>(
      x, ws, EH, AET, WdTm, WdecTm, v_d, b_out, smean, sstd, pmean, out);
}

// Round 6
// 3374.883 us; speedup vs baseline: 4.5008x; 4.5008x over previous
//
#include <hip/hip_runtime.h>
#include <hip/hip_bf16.h>

// Problem constants
#define B_   4096
#define S_   64
#define D_   9
#define H_   128
#define HZ_  32
#define DT_  0.1f

// f32 region layout (float offsets). Regions overlap in TIME, never within a kernel:
//  [0..49152)        : encoder tables WET/VET/WENCT head -> later pvsG (f32 4096*12)
#define OFF_WET    0          // 16384 (encoder only)
#define OFF_VET    16384      // 4096  (encoder only)
#define OFF_WENCT  20480      // 70144 (encoder only)
#define OFF_BENC   90624      // 512   (encoder only)
#define OFF_WDT    91136      // 32768 f32 slot -> hosts WdTm (bf16, 32768 ush) after prep
#define OFF_WDECT  123904     // 135680 f32 slot -> hosts WdecTm (bf16, 147456 ush) after prep
#define OFF_BDEC   259584     // 512   (live, gemm)
#define OFF_WOUTT  260096     // 768   (live, gemm)
#define OFF_VDT    260864     // 16384 (attnenc only)
#define OFF_DECD   277248     // 524288 f32 slot -> hosts dG (524288 ush) + ctxG (524288 ush)
#define OFF_DECC   801536     // 524288 : live c-state f32 (cG)
#define F32_TOTAL  1325824
#define PREP_N     277248

// ushort region after f32 region: EH (33554432) | AET (33554432) | adG (524288)

#define ENC_M 8

typedef __bf16 bf16x8 __attribute__((ext_vector_type(8)));
typedef float  f32x4  __attribute__((ext_vector_type(4)));

__device__ __forceinline__ float fast_tanh(float x) {
    float e = __expf(2.0f * x);
    return 1.0f - __fdividef(2.0f, e + 1.0f);
}
__device__ __forceinline__ float sigf(float x) {
    return __fdividef(1.0f, 1.0f + __expf(-x));
}
__device__ __forceinline__ float wred_sum(float v) {
    #pragma unroll
    for (int off = 32; off; off >>= 1) v += __shfl_xor(v, off, 64);
    return v;
}
__device__ __forceinline__ float bf_lo(unsigned int u) { return __uint_as_float(u << 16); }
__device__ __forceinline__ float bf_hi(unsigned int u) { return __uint_as_float(u & 0xffff0000u); }
__device__ __forceinline__ unsigned short f2bfu(float f) {
    __hip_bfloat16 b = __float2bfloat16(f);
    return *(unsigned short*)&b;
}
__device__ __forceinline__ unsigned int pack_bf(float lo, float hi) {
    return (unsigned int)f2bfu(lo) | ((unsigned int)f2bfu(hi) << 16);
}

// ---------------------------------------------------------------- prep (f32 tables; legacy WDT/WDECT
// slots get overwritten by prep_mfma afterwards — prep MUST run first)
__global__ void prep_kernel(const float* __restrict__ Wih_e, const float* __restrict__ Whh_e,
    const float* __restrict__ bih_e, const float* __restrict__ bhh_e,
    const float* __restrict__ W_e, const float* __restrict__ V_e,
    const float* __restrict__ W_d, const float* __restrict__ V_d,
    const float* __restrict__ Wih_d, const float* __restrict__ Whh_d,
    const float* __restrict__ bih_d, const float* __restrict__ bhh_d,
    const float* __restrict__ W_out, float* __restrict__ ws) {
  for (int idx = blockIdx.x * blockDim.x + threadIdx.x; idx < PREP_N;
       idx += gridDim.x * blockDim.x) {
    int i = idx;
    if (i < 16384) { int k = i >> 6, s = i & 63; ws[OFF_WET + i] = W_e[s * 256 + k]; continue; }
    i -= 16384;
    if (i < 4096) { int s = i >> 6, t = i & 63; ws[OFF_VET + i] = V_e[t * 64 + s]; continue; }
    i -= 4096;
    if (i < 70144) {
      int k = i / 512, g = i & 511;
      ws[OFF_WENCT + i] = (k < 128) ? Whh_e[g * 128 + k] : Wih_e[g * 9 + (k - 128)];
      continue;
    }
    i -= 70144;
    if (i < 512) { ws[OFF_BENC + i] = bih_e[i] + bhh_e[i]; continue; }
    i -= 512;
    if (i < 32768) { continue; }   // legacy WDT slot — now WdTm home
    i -= 32768;
    if (i < 135680) { continue; }  // legacy WDECT slot — now WdecTm home
    i -= 135680;
    if (i < 512) { ws[OFF_BDEC + i] = bih_d[i] + bhh_d[i]; continue; }
    i -= 512;
    if (i < 768) { int k = i / 3, j = i % 3; ws[OFF_WOUTT + i] = W_out[j * 256 + k]; continue; }
    i -= 768;
    { int ii = i >> 7, j = i & 127; ws[OFF_VDT + i] = V_d[j * 128 + ii]; }
  }
}

// ---------------------------------------------------------------- prep (MFMA B-fragment bf16 weights)
__global__ void prep_mfma_kernel(const float* __restrict__ W_d,
    const float* __restrict__ Wih_d, const float* __restrict__ Whh_d,
    unsigned short* __restrict__ WdTm, unsigned short* __restrict__ WdecTm) {
  int idx = blockIdx.x * blockDim.x + threadIdx.x;
  if (idx < 32768) {
    int j = idx & 7, l = (idx >> 3) & 63, t = idx >> 9;
    int nt = t & 7, ks = t >> 3;
    int k = ks * 32 + (l >> 4) * 8 + j;
    int n = nt * 16 + (l & 15);
    WdTm[idx] = f2bfu(W_d[n * 256 + k]);
    return;
  }
  int i2 = idx - 32768;
  if (i2 < 147456) {
    int j = i2 & 7, l = (i2 >> 3) & 63, t = i2 >> 9;   // t in [0,288)
    int ks = t % 9, tile = t / 9;
    int q = tile & 3, is = tile >> 2;
    int k = ks * 32 + (l >> 4) * 8 + j;
    int g = q * 128 + is * 16 + (l & 15);
    float v;
    if (k < 128)      v = Whh_d[g * 128 + k];
    else if (k < 256) v = Wih_d[g * 137 + 9 + (k - 128)];
    else if (k < 265) v = Wih_d[g * 137 + (k - 256)];
    else              v = 0.f;
    WdecTm[i2] = f2bfu(v);
  }
}

// ---------------------------------------------------------------- encoder (R1 proven form)
// Final state: dG (bf16) + cG (f32) — no f32 decd buffer anymore.
__global__ __launch_bounds__(256, 2) void encoder_kernel(
    const float* __restrict__ x_in, const float* __restrict__ ws,
    const float* __restrict__ v_e_g, __hip_bfloat16* __restrict__ EH,
    unsigned short* __restrict__ dG, float* __restrict__ cG) {
  __shared__ float hc[ENC_M][272];
  __shared__ float xb[ENC_M][576];
  __shared__ float ai[ENC_M][576];
  __shared__ float ah[ENC_M][64];
  __shared__ float gl[ENC_M][512];
  __shared__ float ve[64];

  const int tid = threadIdx.x;
  const int b0 = blockIdx.x * ENC_M;
  const int lane = tid & 63, wv = tid >> 6;

  for (int i = tid; i < ENC_M * 576; i += 256) {
    int m = i / 576, r = i % 576;
    xb[m][r] = x_in[(size_t)(b0 + m) * 576 + r];
  }
  if (tid < 64) ve[tid] = v_e_g[tid];
  for (int i = tid; i < ENC_M * 256; i += 256) { int m = i >> 8, r = i & 255; hc[m][r] = 0.f; }
  __syncthreads();

  const float* __restrict__ VeT = ws + OFF_VET;
  for (int i = tid; i < ENC_M * 576; i += 256) {
    int t = i & 63, dd = (i >> 6) % 9, m = i / 576;
    float acc = 0.f;
    for (int s = 0; s < 64; ++s) acc += xb[m][s * 9 + dd] * VeT[s * 64 + t];
    ai[m][dd * 64 + t] = acc;
  }
  __syncthreads();

  const float* __restrict__ WeT   = ws + OFF_WET;
  const float* __restrict__ WencT = ws + OFF_WENCT;
  const float* __restrict__ benc  = ws + OFF_BENC;

  for (int t = 0; t < S_; ++t) {
    {
      const int s = lane, m0 = wv, m1 = wv + 4;
      float a0 = 0.f, a1 = 0.f;
      for (int k = 0; k < 256; k += 4) {
        float w0 = WeT[(k + 0) * 64 + s], w1 = WeT[(k + 1) * 64 + s];
        float w2 = WeT[(k + 2) * 64 + s], w3 = WeT[(k + 3) * 64 + s];
        const float4 h0 = *(const float4*)&hc[m0][k];
        const float4 h1 = *(const float4*)&hc[m1][k];
        a0 += w0 * h0.x + w1 * h0.y + w2 * h0.z + w3 * h0.w;
        a1 += w0 * h1.x + w1 * h1.y + w2 * h1.z + w3 * h1.w;
      }
      ah[m0][s] = a0; ah[m1][s] = a1;
    }
    __syncthreads();
    #pragma unroll
    for (int half = 0; half < 2; ++half) {
      const int mi = wv + half * 4;
      float e_reg = -1e30f;
      for (int dd = 0; dd < 9; ++dd) {
        float a  = ah[mi][lane] + ai[mi][dd * 64 + lane];
        float tv = fast_tanh(a) * ve[lane];
        float e_dd = wred_sum(tv);
        if (lane == dd) e_reg = e_dd;
      }
      float mval = e_reg;
      #pragma unroll
      for (int off = 8; off; off >>= 1) mval = fmaxf(mval, __shfl_xor(mval, off, 64));
      float ex = (lane < 9) ? __expf(e_reg - mval) : 0.f;
      float ssum = ex;
      #pragma unroll
      for (int off = 8; off; off >>= 1) ssum += __shfl_xor(ssum, off, 64);
      if (lane < 9) hc[mi][256 + lane] = __fdividef(ex, ssum) * xb[mi][t * 9 + lane];
    }
    __syncthreads();
    {
      const int g0 = tid, g1 = tid + 256;
      float acc0[ENC_M], acc1[ENC_M];
      const float bb0 = benc[g0], bb1 = benc[g1];
      #pragma unroll
      for (int m = 0; m < ENC_M; ++m) { acc0[m] = bb0; acc1[m] = bb1; }
      for (int k = 0; k < 128; k += 4) {
        float w00 = WencT[(k + 0) * 512 + g0], w01 = WencT[(k + 0) * 512 + g1];
        float w10 = WencT[(k + 1) * 512 + g0], w11 = WencT[(k + 1) * 512 + g1];
        float w20 = WencT[(k + 2) * 512 + g0], w21 = WencT[(k + 2) * 512 + g1];
        float w30 = WencT[(k + 3) * 512 + g0], w31 = WencT[(k + 3) * 512 + g1];
        #pragma unroll
        for (int m = 0; m < ENC_M; ++m) {
          const float4 hv = *(const float4*)&hc[m][k];
          acc0[m] += w00 * hv.x + w10 * hv.y + w20 * hv.z + w30 * hv.w;
          acc1[m] += w01 * hv.x + w11 * hv.y + w21 * hv.z + w31 * hv.w;
        }
      }
      #pragma unroll
      for (int k = 0; k < 9; ++k) {
        float w0 = WencT[(128 + k) * 512 + g0], w1 = WencT[(128 + k) * 512 + g1];
        #pragma unroll
        for (int m = 0; m < ENC_M; ++m) {
          float xv = hc[m][256 + k];
          acc0[m] += w0 * xv; acc1[m] += w1 * xv;
        }
      }
      #pragma unroll
      for (int m = 0; m < ENC_M; ++m) { gl[m][g0] = acc0[m]; gl[m][g1] = acc1[m]; }
    }
    __syncthreads();
    #pragma unroll
    for (int q = 0; q < 4; ++q) {
      int flat = tid + q * 256;
      int m = flat >> 7, i = flat & 127;
      float gi = gl[m][i], gf = gl[m][128 + i], gg = gl[m][256 + i], go = gl[m][384 + i];
      float co = hc[m][128 + i];
      float cn = sigf(gf) * co + sigf(gi) * fast_tanh(gg);
      float hn = sigf(go) * fast_tanh(cn);
      hc[m][i] = hn; hc[m][128 + i] = cn;
      EH[((size_t)(b0 + m) * S_ + t) * H_ + i] = __float2bfloat16(hn);
    }
    __syncthreads();
  }
  #pragma unroll
  for (int q = 0; q < 4; ++q) {
    int flat = tid + q * 256;
    int m = flat >> 7, i = flat & 127;
    dG[(size_t)(b0 + m) * H_ + i] = f2bfu(hc[m][i]);
    cG[(size_t)(b0 + m) * H_ + i] = hc[m][128 + i];
  }
}

// ---------------------------------------------------------------- attn_encoder^T (k-packed, proven)
__global__ __launch_bounds__(256, 4) void attnenc_t_kernel(const float* __restrict__ ws,
    const __hip_bfloat16* __restrict__ EH, unsigned short* __restrict__ AET) {
  __shared__ float EHsT[128 * 65];
  const int tid = threadIdx.x;
  const int b = blockIdx.x;
  const int s = tid & 63, kq = tid >> 6;

  for (int flat = tid; flat < 8192; flat += 256) {
    int ss = flat >> 7, ii = flat & 127;
    EHsT[ii * 65 + ss] = __bfloat162float(EH[(size_t)b * 8192 + flat]);
  }
  __syncthreads();

  const float* __restrict__ VdT = ws + OFF_VDT;
  float4 acc[8];
  #pragma unroll
  for (int g = 0; g < 8; ++g) acc[g] = make_float4(0.f, 0.f, 0.f, 0.f);
  for (int i = 0; i < 128; ++i) {
    float e = EHsT[i * 65 + s];
    const float4* w4 = (const float4*)(VdT + i * 128 + kq * 32);
    #pragma unroll
    for (int g = 0; g < 8; ++g) {
      float4 w = w4[g];
      acc[g].x += e * w.x; acc[g].y += e * w.y; acc[g].z += e * w.z; acc[g].w += e * w.w;
    }
  }
  unsigned short* outp = AET + (size_t)b * 8192;
  #pragma unroll
  for (int g = 0; g < 4; ++g) {
    float4 a0 = acc[2 * g], a1 = acc[2 * g + 1];
    uint4 pk;
    pk.x = pack_bf(a0.x, a0.y); pk.y = pack_bf(a0.z, a0.w);
    pk.z = pack_bf(a1.x, a1.y); pk.w = pack_bf(a1.z, a1.w);
    *(uint4*)(outp + (size_t)(kq * 4 + g) * 512 + s * 8) = pk;
  }
}

// ---------------------------------------------------------------- decoder init: pvsG + ad0 (MFMA)
__global__ __launch_bounds__(256) void init_dec_kernel(
    const float* __restrict__ x_in,
    const unsigned short* __restrict__ dG, const float* __restrict__ cG,
    const unsigned short* __restrict__ WdTm,
    const float* __restrict__ smean_g, const float* __restrict__ sstd_g,
    const float* __restrict__ pmean_g,
    unsigned short* __restrict__ adG, float* __restrict__ pvsG) {
  __shared__ unsigned short dcB[16 * 264];
  const int tid = threadIdx.x;
  const int b0 = blockIdx.x * 16;
  const int l = tid & 63, w = tid >> 6;
  const int quad = l >> 4, l15 = l & 15;

  {
    int m = tid >> 4, i0 = (tid & 15) * 8;
    *(uint4*)&dcB[m * 264 + i0] = *(const uint4*)(dG + (size_t)(b0 + m) * 128 + i0);
    float4 c0 = *(const float4*)(cG + (size_t)(b0 + m) * 128 + i0);
    float4 c1 = *(const float4*)(cG + (size_t)(b0 + m) * 128 + i0 + 4);
    uint4 pk;
    pk.x = pack_bf(c0.x, c0.y); pk.y = pack_bf(c0.z, c0.w);
    pk.z = pack_bf(c1.x, c1.y); pk.w = pack_bf(c1.z, c1.w);
    *(uint4*)&dcB[m * 264 + 128 + i0] = pk;
  }
  if (tid < 48) {
    int m = tid / 3, jj = tid % 3;
    const float* xi = x_in + (size_t)(b0 + m) * 576;
    float sm = smean_g[jj], ss = sstd_g[jj], pm = pmean_g[jj];
    float v  = xi[63 * 9 + 3 + jj] * ss + sm;
    float pv = xi[62 * 9 + 3 + jj] * ss + sm;
    float* P = pvsG + (size_t)(b0 + m) * 12;
    P[jj] = xi[63 * 9 + jj] + pm;
    P[3 + jj] = v;
    P[6 + jj] = (v - pv) / DT_;
  }
  __syncthreads();
  #pragma unroll
  for (int t = 0; t < 2; ++t) {
    const int nt = w + 4 * t;
    f32x4 acc = {0.f, 0.f, 0.f, 0.f};
    #pragma unroll
    for (int ks = 0; ks < 8; ++ks) {
      uint4 au = *(const uint4*)&dcB[l15 * 264 + ks * 32 + quad * 8];
      uint4 bu = *(const uint4*)(WdTm + (size_t)((ks * 8 + nt) * 64 + l) * 8);
      acc = __builtin_amdgcn_mfma_f32_16x16x32_bf16(
          __builtin_bit_cast(bf16x8, au), __builtin_bit_cast(bf16x8, bu), acc, 0, 0, 0);
    }
    int n = nt * 16 + l15;
    #pragma unroll
    for (int r = 0; r < 4; ++r)
      adG[(size_t)(b0 + quad * 4 + r) * 128 + n] = f2bfu(acc[r]);
  }
}

// ---------------------------------------------------------------- per-step attention (streaming)
// grid 2048 x 256 thr. 2 batches/block; wave w: ml=w>>1, half=w&1.
__global__ __launch_bounds__(256, 8) void attn_step_kernel(
    const unsigned short* __restrict__ AET, const unsigned short* __restrict__ EH,
    const unsigned short* __restrict__ adG, const float* __restrict__ v_d_g,
    unsigned short* __restrict__ ctxG) {
  __shared__ unsigned short adL[2 * 128];
  __shared__ float vdL[128];
  __shared__ float scp[2][2][64];
  __shared__ float bet[2][64];
  __shared__ float ctxP[2][2][128];

  const int tid = threadIdx.x;
  const int b0 = blockIdx.x * 2;
  const int l = tid & 63, w = tid >> 6;
  const int ml = w >> 1, half = w & 1;
  const int quad = l >> 4, l15 = l & 15;

  if (tid < 32)
    *(uint4*)&adL[tid * 8] = *(const uint4*)(adG + (size_t)(b0 + (tid >> 4)) * 128 + (tid & 15) * 8);
  if (tid < 128) vdL[tid] = v_d_g[tid];
  __syncthreads();

  // scores: lane = s, partial over k-half
  {
    const unsigned short* aet = AET + (size_t)(b0 + ml) * 8192 + (size_t)half * 8 * 512;
    const unsigned short* adp = adL + ml * 128 + half * 64;
    float e = 0.f;
    #pragma unroll
    for (int kb = 0; kb < 8; ++kb) {
      uint4 av  = *(const uint4*)(aet + kb * 512 + l * 8);
      uint4 ad8 = *(const uint4*)(adp + kb * 8);
      float4 v0 = *(const float4*)&vdL[half * 64 + kb * 8];
      float4 v1 = *(const float4*)&vdL[half * 64 + kb * 8 + 4];
      e += fast_tanh(bf_lo(ad8.x) + bf_lo(av.x)) * v0.x;
      e += fast_tanh(bf_hi(ad8.x) + bf_hi(av.x)) * v0.y;
      e += fast_tanh(bf_lo(ad8.y) + bf_lo(av.y)) * v0.z;
      e += fast_tanh(bf_hi(ad8.y) + bf_hi(av.y)) * v0.w;
      e += fast_tanh(bf_lo(ad8.z) + bf_lo(av.z)) * v1.x;
      e += fast_tanh(bf_hi(ad8.z) + bf_hi(av.z)) * v1.y;
      e += fast_tanh(bf_lo(ad8.w) + bf_lo(av.w)) * v1.z;
      e += fast_tanh(bf_hi(ad8.w) + bf_hi(av.w)) * v1.w;
    }
    scp[ml][half][l] = e;
  }
  __syncthreads();
  if (half == 0) {
    float e = scp[ml][0][l] + scp[ml][1][l];
    float mx = e;
    #pragma unroll
    for (int off = 32; off; off >>= 1) mx = fmaxf(mx, __shfl_xor(mx, off, 64));
    float ex = __expf(e - mx);
    float ss = ex;
    #pragma unroll
    for (int off = 32; off; off >>= 1) ss += __shfl_xor(ss, off, 64);
    bet[ml][l] = __fdividef(ex, ss);
  }
  __syncthreads();
  // context partial over s-half
  {
    const unsigned short* base = EH + (size_t)(b0 + ml) * 8192 + (size_t)half * 32 * 128;
    float a[8];
    #pragma unroll
    for (int r = 0; r < 8; ++r) a[r] = 0.f;
    #pragma unroll
    for (int it = 0; it < 8; ++it) {
      int sl = it * 4 + quad;
      uint4 ev = *(const uint4*)(base + sl * 128 + l15 * 8);
      float bt = bet[ml][half * 32 + sl];
      a[0] += bt * bf_lo(ev.x); a[1] += bt * bf_hi(ev.x);
      a[2] += bt * bf_lo(ev.y); a[3] += bt * bf_hi(ev.y);
      a[4] += bt * bf_lo(ev.z); a[5] += bt * bf_hi(ev.z);
      a[6] += bt * bf_lo(ev.w); a[7] += bt * bf_hi(ev.w);
    }
    #pragma unroll
    for (int r = 0; r < 8; ++r) {
      a[r] += __shfl_xor(a[r], 16, 64);
      a[r] += __shfl_xor(a[r], 32, 64);
    }
    if (quad == 0) {
      *(float4*)&ctxP[ml][half][l15 * 8]     = make_float4(a[0], a[1], a[2], a[3]);
      *(float4*)&ctxP[ml][half][l15 * 8 + 4] = make_float4(a[4], a[5], a[6], a[7]);
    }
  }
  __syncthreads();
  if (tid < 128) {
    int mi = tid >> 6, hp = (tid & 63) * 2;
    float c0 = ctxP[mi][0][hp]     + ctxP[mi][1][hp];
    float c1 = ctxP[mi][0][hp + 1] + ctxP[mi][1][hp + 1];
    *(unsigned int*)(ctxG + (size_t)(b0 + mi) * 128 + hp) = pack_bf(c0, c1);
  }
}

// ---------------------------------------------------------------- per-step GEMM: gates+LSTM+out+next ad
// grid 256 x 512 thr (8 waves). 16 batches/block.
__global__ __launch_bounds__(512, 2) void gemm_step_kernel(
    const float* __restrict__ ws,
    const unsigned short* __restrict__ dG_in, float* __restrict__ cG,
    const unsigned short* __restrict__ ctxG,
    const unsigned short* __restrict__ WdTm, const unsigned short* __restrict__ WdecTm,
    unsigned short* __restrict__ dG_out, unsigned short* __restrict__ adG,
    float* __restrict__ pvsG,
    const float* __restrict__ b_out_g, const float* __restrict__ smean_g,
    const float* __restrict__ sstd_g, const float* __restrict__ pmean_g,
    float* __restrict__ out, int hz) {
  __shared__ unsigned short gA[16 * 296];   // [d 0..127 | ctx 128..255 | phys 256..264 | zero 265..295]
  __shared__ unsigned short dcB[16 * 264];  // new [d | c] for next-ad MFMA
  __shared__ float pd[16 * 3 * 8];
  __shared__ float pc[16 * 3 * 4];

  const int tid = threadIdx.x;
  const int b0 = blockIdx.x * 16;
  const int l = tid & 63, w = tid >> 6;
  const int quad = l >> 4, l15 = l & 15;

  // ---- stage (gA fully defined: d from dG, ctx from ctxG, phys, zero pad for ALL 16 rows)
  if (tid < 256) {
    int m = tid >> 4, i0 = (tid & 15) * 8;
    *(uint4*)&gA[m * 296 + i0] = *(const uint4*)(dG_in + (size_t)(b0 + m) * 128 + i0);
  } else {
    int t = tid - 256;
    int m = t >> 4, i0 = (t & 15) * 8;
    *(uint4*)&gA[m * 296 + 128 + i0] = *(const uint4*)(ctxG + (size_t)(b0 + m) * 128 + i0);
  }
  if (tid < 496) { int mm = tid / 31, r = tid % 31; gA[mm * 296 + 265 + r] = 0; }  // all 16 rows
  if (tid < 48) {
    int m = tid / 3, jj = tid % 3;
    const float* P = pvsG + (size_t)(b0 + m) * 12;
    float sm = smean_g[jj], ss = sstd_g[jj], pm = pmean_g[jj];
    gA[m * 296 + 256 + jj]     = f2bfu(P[jj] - pm);
    gA[m * 296 + 256 + 3 + jj] = f2bfu((P[3 + jj] - sm) / ss);
    gA[m * 296 + 256 + 6 + jj] = f2bfu(P[6 + jj] / ss);
  }
  __syncthreads();

  // ---- D+E: gates (gate-permuted MFMA) + in-register LSTM. wave w -> i-slice w.
  // NOTE: writes new d/c ONLY to dcB + globals (gA untouched -> no read/write race).
  {
    uint4 af[9];
    #pragma unroll
    for (int ks = 0; ks < 9; ++ks)
      af[ks] = *(const uint4*)&gA[l15 * 296 + ks * 32 + quad * 8];
    const int is = w, i = is * 16 + l15;
    float bb[4], wd[3];
    #pragma unroll
    for (int q = 0; q < 4; ++q) bb[q] = ws[OFF_BDEC + q * 128 + i];
    #pragma unroll
    for (int jj = 0; jj < 3; ++jj) wd[jj] = ws[OFF_WOUTT + i * 3 + jj];
    f32x4 g4[4];
    #pragma unroll
    for (int q = 0; q < 4; ++q) {
      f32x4 acc = {0.f, 0.f, 0.f, 0.f};
      #pragma unroll
      for (int ks = 0; ks < 9; ++ks) {
        uint4 bu = *(const uint4*)(WdecTm + (size_t)(((is * 4 + q) * 9 + ks) * 64 + l) * 8);
        acc = __builtin_amdgcn_mfma_f32_16x16x32_bf16(
            __builtin_bit_cast(bf16x8, af[ks]), __builtin_bit_cast(bf16x8, bu), acc, 0, 0, 0);
      }
      g4[q] = acc;
    }
    float pr[4][3];
    #pragma unroll
    for (int r = 0; r < 4; ++r) {
      int m = quad * 4 + r;
      float gi = g4[0][r] + bb[0];
      float gf = g4[1][r] + bb[1];
      float gg = g4[2][r] + bb[2];
      float go = g4[3][r] + bb[3];
      float co = cG[(size_t)(b0 + m) * 128 + i];
      float cn = sigf(gf) * co + sigf(gi) * fast_tanh(gg);
      float hn = sigf(go) * fast_tanh(cn);
      cG[(size_t)(b0 + m) * 128 + i] = cn;
      unsigned short hb = f2bfu(hn);
      dG_out[(size_t)(b0 + m) * 128 + i] = hb;
      dcB[m * 264 + i] = hb;
      dcB[m * 264 + 128 + i] = f2bfu(cn);
      pr[r][0] = hn * wd[0]; pr[r][1] = hn * wd[1]; pr[r][2] = hn * wd[2];
    }
    #pragma unroll
    for (int r = 0; r < 4; ++r)
      #pragma unroll
      for (int jj = 0; jj < 3; ++jj) {
        float v = pr[r][jj];
        #pragma unroll
        for (int off = 8; off; off >>= 1) v += __shfl_xor(v, off, 64);
        pr[r][jj] = v;
      }
    if (l15 == 0) {
      #pragma unroll
      for (int r = 0; r < 4; ++r)
        #pragma unroll
        for (int jj = 0; jj < 3; ++jj)
          pd[((quad * 4 + r) * 3 + jj) * 8 + is] = pr[r][jj];
    }
  }
  __syncthreads();

  // ---- A: next-step attn_dec = [d_new; c_new] @ W_d^T (MFMA). wave w -> nt=w.
  {
    const int nt = w;
    f32x4 acc = {0.f, 0.f, 0.f, 0.f};
    #pragma unroll
    for (int ks = 0; ks < 8; ++ks) {
      uint4 au = *(const uint4*)&dcB[l15 * 264 + ks * 32 + quad * 8];
      uint4 bu = *(const uint4*)(WdTm + (size_t)((ks * 8 + nt) * 64 + l) * 8);
      acc = __builtin_amdgcn_mfma_f32_16x16x32_bf16(
          __builtin_bit_cast(bf16x8, au), __builtin_bit_cast(bf16x8, bu), acc, 0, 0, 0);
    }
    int n = nt * 16 + l15;
    #pragma unroll
    for (int r = 0; r < 4; ++r) {
      int m = quad * 4 + r;
      adG[(size_t)(b0 + m) * 128 + n] = f2bfu(acc[r]);
    }
  }
  // pc: ctx part of pred_acc (gA ctx unchanged since staging)
  if (tid < 192) {
    int m = tid / 12, jj = (tid % 12) / 4, part = tid % 4;
    int k0 = part * 32;
    float acc = 0.f;
    for (int k = k0; k < k0 + 32; ++k) {
      __hip_bfloat16 hv = *(__hip_bfloat16*)&gA[m * 296 + 128 + k];
      acc += __bfloat162float(hv) * ws[OFF_WOUTT + 384 + k * 3 + jj];
    }
    pc[(m * 3 + jj) * 4 + part] = acc;
  }
  __syncthreads();

  // ---- G: Verlet + output + pvs writeback
  if (tid < 48) {
    int m = tid / 3, jj = tid % 3;
    float s = b_out_g[jj];
    #pragma unroll
    for (int p = 0; p < 4; ++p) s += pc[(m * 3 + jj) * 4 + p];
    #pragma unroll
    for (int is = 0; is < 8; ++is) s += pd[(m * 3 + jj) * 8 + is];
    float pacc = s * sstd_g[jj];
    float* P = pvsG + (size_t)(b0 + m) * 12;
    float pos = P[jj], vel = P[3 + jj], acc = P[6 + jj];
    float ppred = pos + vel * DT_ + 0.5f * acc * DT_ * DT_;
    float vnew  = vel + 0.5f * (acc + pacc) * DT_;
    size_t ob = ((size_t)(b0 + m) * HZ_ + hz) * 9;
    out[ob + jj] = ppred; out[ob + 3 + jj] = vnew; out[ob + 6 + jj] = pacc;
    P[jj] = ppred; P[3 + jj] = vnew; P[6 + jj] = pacc;
  }
}

// ---------------------------------------------------------------- launch
extern "C" void kernel_launch(void* const* d_in, const int* in_sizes, int n_in,
                              void* d_out, int out_size, void* d_ws, size_t ws_size,
                              hipStream_t stream) {
  (void)in_sizes; (void)n_in; (void)out_size; (void)ws_size;
  const float* x      = (const float*)d_in[0];
  const float* Wih_e  = (const float*)d_in[1];
  const float* Whh_e  = (const float*)d_in[2];
  const float* bih_e  = (const float*)d_in[3];
  const float* bhh_e  = (const float*)d_in[4];
  const float* W_e    = (const float*)d_in[5];
  const float* V_e    = (const float*)d_in[6];
  const float* v_e    = (const float*)d_in[7];
  const float* W_d    = (const float*)d_in[8];
  const float* V_d    = (const float*)d_in[9];
  const float* v_d    = (const float*)d_in[10];
  const float* Wih_d  = (const float*)d_in[11];
  const float* Whh_d  = (const float*)d_in[12];
  const float* bih_d  = (const float*)d_in[13];
  const float* bhh_d  = (const float*)d_in[14];
  const float* W_out  = (const float*)d_in[15];
  const float* b_out  = (const float*)d_in[16];
  const float* smean  = (const float*)d_in[17];
  const float* sstd   = (const float*)d_in[18];
  const float* pmean  = (const float*)d_in[19];

  float* ws = (float*)d_ws;
  // overlays within f32 region
  float* pvsG = ws;                                          // over WET/VET/WENCT (dead post-encoder)
  unsigned short* WdTm   = (unsigned short*)(ws + OFF_WDT);  // over legacy WDT slot
  unsigned short* WdecTm = (unsigned short*)(ws + OFF_WDECT);// over legacy WDECT slot
  unsigned short* dG     = (unsigned short*)(ws + OFF_DECD); // 524288 ush
  unsigned short* ctxG   = dG + 524288;                      // 524288 ush (fills DECD slot)
  float* cG = ws + OFF_DECC;
  // ushort region
  unsigned short* ub  = (unsigned short*)(ws + F32_TOTAL);
  unsigned short* EH  = ub;
  unsigned short* AET = ub + 33554432;
  unsigned short* adG = ub + 67108864;
  float* out = (float*)d_out;

  prep_kernel<<<(PREP_N + 255) / 256, 256, 0, stream>>>(
      Wih_e, Whh_e, bih_e, bhh_e, W_e, V_e, W_d, V_d,
      Wih_d, Whh_d, bih_d, bhh_d, W_out, ws);
  prep_mfma_kernel<<<(32768 + 147456 + 255) / 256, 256, 0, stream>>>(
      W_d, Wih_d, Whh_d, WdTm, WdecTm);
  encoder_kernel<<<B_ / ENC_M, 256, 0, stream>>>(
      x, ws, v_e, (__hip_bfloat16*)EH, dG, cG);
  attnenc_t_kernel<<<B_, 256, 0, stream>>>(ws, (const __hip_bfloat16*)EH, AET);
  init_dec_kernel<<<B_ / 16, 256, 0, stream>>>(
      x, dG, cG, WdTm, smean, sstd, pmean, adG, pvsG);
  for (int hz = 0; hz < HZ_; ++hz) {
    attn_step_kernel<<<B_ / 2, 256, 0, stream>>>(AET, EH, adG, v_d, ctxG);
    gemm_step_kernel<<<B_ / 16, 512, 0, stream>>>(
        ws, dG, cG, ctxG, WdTm, WdecTm, dG, adG, pvsG,
        b_out, smean, sstd, pmean, out, hz);
  }
}

// Round 7
// 2343.784 us; speedup vs baseline: 6.4808x; 1.4399x over previous
//
#include <hip/hip_runtime.h>
#include <hip/hip_bf16.h>

// Problem constants
#define B_   4096
#define S_   64
#define D_   9
#define H_   128
#define HZ_  32
#define DT_  0.1f

// f32 region layout (float offsets). Regions overlap in TIME, never within a kernel:
//  [0..49152)      : encoder bf16 tables (WeTm @WET slot, WencTm @WENCT slot) -> later pvsG
#define OFF_WET    0          // slot hosts WeTm  (bf16, 16384 ush) [encoder only]
#define OFF_VET    16384      // 4096 f32 V_e^T   [encoder only]
#define OFF_WENCT  20480      // slot hosts WencTm (bf16, 81920 ush) [encoder only]
#define OFF_BENC   90624      // 512   [encoder only]
#define OFF_WDT    91136      // slot hosts WdTm (bf16, 32768 ush)
#define OFF_WDECT  123904     // slot hosts WdecTm (bf16, 147456 ush)
#define OFF_BDEC   259584     // 512   (live, gemm)
#define OFF_WOUTT  260096     // 768   (live, gemm)
#define OFF_VDT    260864     // 16384 (attnenc only)
#define OFF_DECD   277248     // slot hosts dG (524288 ush) + ctxG (524288 ush)
#define OFF_DECC   801536     // 524288 : live c-state f32 (cG)
#define F32_TOTAL  1325824
#define PREP_N     277248

// ushort region after f32 region: EH (33554432) | AET (33554432) | adG (524288)

typedef __bf16 bf16x8 __attribute__((ext_vector_type(8)));
typedef float  f32x4  __attribute__((ext_vector_type(4)));

__device__ __forceinline__ float fast_tanh(float x) {
    float e = __expf(2.0f * x);
    return 1.0f - __fdividef(2.0f, e + 1.0f);
}
__device__ __forceinline__ float sigf(float x) {
    return __fdividef(1.0f, 1.0f + __expf(-x));
}
__device__ __forceinline__ float bf_lo(unsigned int u) { return __uint_as_float(u << 16); }
__device__ __forceinline__ float bf_hi(unsigned int u) { return __uint_as_float(u & 0xffff0000u); }
__device__ __forceinline__ unsigned short f2bfu(float f) {
    __hip_bfloat16 b = __float2bfloat16(f);
    return *(unsigned short*)&b;
}
__device__ __forceinline__ unsigned int pack_bf(float lo, float hi) {
    return (unsigned int)f2bfu(lo) | ((unsigned int)f2bfu(hi) << 16);
}

// ---------------------------------------------------------------- prep (f32 tables)
__global__ void prep_kernel(const float* __restrict__ Wih_e, const float* __restrict__ Whh_e,
    const float* __restrict__ bih_e, const float* __restrict__ bhh_e,
    const float* __restrict__ W_e, const float* __restrict__ V_e,
    const float* __restrict__ W_d, const float* __restrict__ V_d,
    const float* __restrict__ Wih_d, const float* __restrict__ Whh_d,
    const float* __restrict__ bih_d, const float* __restrict__ bhh_d,
    const float* __restrict__ W_out, float* __restrict__ ws) {
  for (int idx = blockIdx.x * blockDim.x + threadIdx.x; idx < PREP_N;
       idx += gridDim.x * blockDim.x) {
    int i = idx;
    if (i < 16384) { continue; }   // WET slot -> WeTm (prep_enc_mfma)
    i -= 16384;
    if (i < 4096) { int s = i >> 6, t = i & 63; ws[OFF_VET + i] = V_e[t * 64 + s]; continue; }
    i -= 4096;
    if (i < 70144) { continue; }   // WENCT slot -> WencTm (prep_enc_mfma)
    i -= 70144;
    if (i < 512) { ws[OFF_BENC + i] = bih_e[i] + bhh_e[i]; continue; }
    i -= 512;
    if (i < 32768) { continue; }   // WDT slot -> WdTm
    i -= 32768;
    if (i < 135680) { continue; }  // WDECT slot -> WdecTm
    i -= 135680;
    if (i < 512) { ws[OFF_BDEC + i] = bih_d[i] + bhh_d[i]; continue; }
    i -= 512;
    if (i < 768) { int k = i / 3, j = i % 3; ws[OFF_WOUTT + i] = W_out[j * 256 + k]; continue; }
    i -= 768;
    { int ii = i >> 7, j = i & 127; ws[OFF_VDT + i] = V_d[j * 128 + ii]; }
  }
}

// ---------------------------------------------------------------- prep decoder MFMA weights
__global__ void prep_mfma_kernel(const float* __restrict__ W_d,
    const float* __restrict__ Wih_d, const float* __restrict__ Whh_d,
    unsigned short* __restrict__ WdTm, unsigned short* __restrict__ WdecTm) {
  int idx = blockIdx.x * blockDim.x + threadIdx.x;
  if (idx < 32768) {
    int j = idx & 7, l = (idx >> 3) & 63, t = idx >> 9;
    int nt = t & 7, ks = t >> 3;
    int k = ks * 32 + (l >> 4) * 8 + j;
    int n = nt * 16 + (l & 15);
    WdTm[idx] = f2bfu(W_d[n * 256 + k]);
    return;
  }
  int i2 = idx - 32768;
  if (i2 < 147456) {
    int j = i2 & 7, l = (i2 >> 3) & 63, t = i2 >> 9;   // t in [0,288)
    int ks = t % 9, tile = t / 9;
    int q = tile & 3, is = tile >> 2;
    int k = ks * 32 + (l >> 4) * 8 + j;
    int g = q * 128 + is * 16 + (l & 15);
    float v;
    if (k < 128)      v = Whh_d[g * 128 + k];
    else if (k < 256) v = Wih_d[g * 137 + 9 + (k - 128)];
    else if (k < 265) v = Wih_d[g * 137 + (k - 256)];
    else              v = 0.f;
    WdecTm[i2] = f2bfu(v);
  }
}

// ---------------------------------------------------------------- prep encoder MFMA weights
// WeTm  : tiles (ks 0..7, nt 0..3): n=nt*16+l15 (s), k=ks*32+(l>>4)*8+j over [h;c]; val=W_e[n][k]
// WencTm: tiles (is 0..7, q 0..3, ks 0..4): i=is*16+l15, g=q*128+i;
//         ks<4 -> Whh_e[g][ks*32+kk]; ks==4 -> kk<9 ? Wih_e[g][kk] : 0
__global__ void prep_enc_mfma_kernel(const float* __restrict__ W_e,
    const float* __restrict__ Wih_e, const float* __restrict__ Whh_e,
    unsigned short* __restrict__ WeTm, unsigned short* __restrict__ WencTm) {
  int idx = blockIdx.x * blockDim.x + threadIdx.x;
  if (idx < 16384) {
    int j = idx & 7, l = (idx >> 3) & 63, tile = idx >> 9;  // ks*4+nt
    int nt = tile & 3, ks = tile >> 2;
    int k = ks * 32 + (l >> 4) * 8 + j;
    int n = nt * 16 + (l & 15);
    WeTm[idx] = f2bfu(W_e[n * 256 + k]);
    return;
  }
  int i2 = idx - 16384;
  if (i2 < 81920) {
    int j = i2 & 7, l = (i2 >> 3) & 63, tile = i2 >> 9;  // (is*4+q)*5+ks
    int ks = tile % 5, tq = tile / 5;
    int q = tq & 3, is = tq >> 2;
    int kk = (l >> 4) * 8 + j;
    int g = q * 128 + is * 16 + (l & 15);
    float v;
    if (ks < 4) v = Whh_e[g * 128 + ks * 32 + kk];
    else        v = (kk < 9) ? Wih_e[g * 9 + kk] : 0.f;
    WencTm[i2] = f2bfu(v);
  }
}

// ---------------------------------------------------------------- encoder (MFMA, 16 batches, 512 thr)
// Per step: P1 ah=[h;c]@W_e^T (MFMA, waves 0-3) | P2 softmax+xs (2 batches/wave) |
// P3 gates (gate-permuted MFMA) + in-register LSTM. h/c double-buffered in LDS -> 3 barriers/step.
__global__ __launch_bounds__(512, 1) void encoder_mfma_kernel(
    const float* __restrict__ x_in, const float* __restrict__ ws,
    const float* __restrict__ v_e_g,
    const unsigned short* __restrict__ WeTm, const unsigned short* __restrict__ WencTm,
    __hip_bfloat16* __restrict__ EH,
    unsigned short* __restrict__ dG, float* __restrict__ cG) {
  __shared__ unsigned short hA[2][16 * 296];  // [h 0..127 | c 128..255 | xs 256..264 | zeros..287]
  __shared__ float cF[16 * 132];
  __shared__ float ahL[16 * 64];
  __shared__ float aiL[16 * 576];
  __shared__ float xbL[16 * 576];

  const int tid = threadIdx.x;
  const int b0 = blockIdx.x * 16;
  const int l = tid & 63, w = tid >> 6;     // 8 waves
  const int quad = l >> 4, l15 = l & 15;

  for (int i = tid; i < 16 * 576; i += 512) {
    int m = i / 576, r = i % 576;
    xbL[i] = x_in[(size_t)(b0 + m) * 576 + r];
  }
  for (int i = tid; i < 2 * 16 * 296; i += 512) ((unsigned short*)hA)[i] = 0;
  for (int i = tid; i < 16 * 132; i += 512) cF[i] = 0.f;
  __syncthreads();

  {
    const float* __restrict__ VeT = ws + OFF_VET;
    for (int i = tid; i < 16 * 576; i += 512) {
      int t = i & 63, dd = (i >> 6) % 9, m = i / 576;
      float acc = 0.f;
      for (int s = 0; s < 64; ++s) acc += xbL[m * 576 + s * 9 + dd] * VeT[s * 64 + t];
      aiL[m * 576 + dd * 64 + t] = acc;
    }
  }
  const float ve_r = v_e_g[l];
  const int ig = w * 16 + l15;                 // gate/i index for P3
  float bbq[4];
  #pragma unroll
  for (int q = 0; q < 4; ++q) bbq[q] = ws[OFF_BENC + q * 128 + ig];
  __syncthreads();

  for (int t = 0; t < S_; ++t) {
    unsigned short* bufC = hA[t & 1];
    unsigned short* bufN = hA[(t + 1) & 1];
    // ---- P1: ah (waves 0..3, nt = w)
    if (w < 4) {
      f32x4 acc = {0.f, 0.f, 0.f, 0.f};
      #pragma unroll
      for (int ks = 0; ks < 8; ++ks) {
        uint4 au = *(const uint4*)&bufC[l15 * 296 + ks * 32 + quad * 8];
        uint4 bu = *(const uint4*)(WeTm + (size_t)((ks * 4 + w) * 64 + l) * 8);
        acc = __builtin_amdgcn_mfma_f32_16x16x32_bf16(
            __builtin_bit_cast(bf16x8, au), __builtin_bit_cast(bf16x8, bu), acc, 0, 0, 0);
      }
      #pragma unroll
      for (int r = 0; r < 4; ++r)
        ahL[(quad * 4 + r) * 64 + w * 16 + l15] = acc[r];
    }
    __syncthreads();
    // ---- P2: scores over d, softmax(9), xs = alpha*x_t (wave w -> batches 2w,2w+1)
    {
      const int m0 = 2 * w, m1 = 2 * w + 1;
      float a0 = ahL[m0 * 64 + l], a1 = ahL[m1 * 64 + l];
      float e0k = -1e30f, e1k = -1e30f;
      #pragma unroll
      for (int dd = 0; dd < 9; ++dd) {
        float t0 = fast_tanh(a0 + aiL[m0 * 576 + dd * 64 + l]) * ve_r;
        float t1 = fast_tanh(a1 + aiL[m1 * 576 + dd * 64 + l]) * ve_r;
        #pragma unroll
        for (int off = 32; off; off >>= 1) {
          t0 += __shfl_xor(t0, off, 64);
          t1 += __shfl_xor(t1, off, 64);
        }
        if (l == dd) { e0k = t0; e1k = t1; }
      }
      float mx0 = e0k, mx1 = e1k;
      #pragma unroll
      for (int off = 8; off; off >>= 1) {
        mx0 = fmaxf(mx0, __shfl_xor(mx0, off, 64));
        mx1 = fmaxf(mx1, __shfl_xor(mx1, off, 64));
      }
      float ex0 = (l < 9) ? __expf(e0k - mx0) : 0.f;
      float ex1 = (l < 9) ? __expf(e1k - mx1) : 0.f;
      float s0 = ex0, s1 = ex1;
      #pragma unroll
      for (int off = 8; off; off >>= 1) {
        s0 += __shfl_xor(s0, off, 64);
        s1 += __shfl_xor(s1, off, 64);
      }
      if (l < 9) {
        bufC[m0 * 296 + 256 + l] = f2bfu(__fdividef(ex0, s0) * xbL[m0 * 576 + t * 9 + l]);
        bufC[m1 * 296 + 256 + l] = f2bfu(__fdividef(ex1, s1) * xbL[m1 * 576 + t * 9 + l]);
      }
    }
    __syncthreads();
    // ---- P3: gates (gate-permuted MFMA, wave w -> i-slice w) + in-register LSTM
    {
      uint4 af[5];
      #pragma unroll
      for (int ks = 0; ks < 4; ++ks)
        af[ks] = *(const uint4*)&bufC[l15 * 296 + ks * 32 + quad * 8];
      af[4] = *(const uint4*)&bufC[l15 * 296 + 256 + quad * 8];
      f32x4 g4[4];
      #pragma unroll
      for (int q = 0; q < 4; ++q) {
        f32x4 acc = {0.f, 0.f, 0.f, 0.f};
        #pragma unroll
        for (int ks = 0; ks < 5; ++ks) {
          uint4 bu = *(const uint4*)(WencTm + (size_t)(((w * 4 + q) * 5 + ks) * 64 + l) * 8);
          acc = __builtin_amdgcn_mfma_f32_16x16x32_bf16(
              __builtin_bit_cast(bf16x8, af[ks]), __builtin_bit_cast(bf16x8, bu), acc, 0, 0, 0);
        }
        g4[q] = acc;
      }
      #pragma unroll
      for (int r = 0; r < 4; ++r) {
        int m = quad * 4 + r;
        float gi = g4[0][r] + bbq[0];
        float gf = g4[1][r] + bbq[1];
        float gg = g4[2][r] + bbq[2];
        float go = g4[3][r] + bbq[3];
        float co = cF[m * 132 + ig];
        float cn = sigf(gf) * co + sigf(gi) * fast_tanh(gg);
        float hn = sigf(go) * fast_tanh(cn);
        cF[m * 132 + ig] = cn;
        bufN[m * 296 + ig] = f2bfu(hn);
        bufN[m * 296 + 128 + ig] = f2bfu(cn);
        EH[((size_t)(b0 + m) * S_ + t) * H_ + ig] = __float2bfloat16(hn);
      }
    }
    __syncthreads();
  }
  // final state: buf0 holds h/c after t=63 (written into hA[(63+1)&1] = hA[0])
  for (int i = tid; i < 16 * 128; i += 512) {
    int m = i >> 7, ii = i & 127;
    dG[(size_t)(b0 + m) * 128 + ii] = hA[0][m * 296 + ii];
    cG[(size_t)(b0 + m) * 128 + ii] = cF[m * 132 + ii];
  }
}

// ---------------------------------------------------------------- attn_encoder^T (k-packed, proven)
__global__ __launch_bounds__(256, 4) void attnenc_t_kernel(const float* __restrict__ ws,
    const __hip_bfloat16* __restrict__ EH, unsigned short* __restrict__ AET) {
  __shared__ float EHsT[128 * 65];
  const int tid = threadIdx.x;
  const int b = blockIdx.x;
  const int s = tid & 63, kq = tid >> 6;

  for (int flat = tid; flat < 8192; flat += 256) {
    int ss = flat >> 7, ii = flat & 127;
    EHsT[ii * 65 + ss] = __bfloat162float(EH[(size_t)b * 8192 + flat]);
  }
  __syncthreads();

  const float* __restrict__ VdT = ws + OFF_VDT;
  float4 acc[8];
  #pragma unroll
  for (int g = 0; g < 8; ++g) acc[g] = make_float4(0.f, 0.f, 0.f, 0.f);
  for (int i = 0; i < 128; ++i) {
    float e = EHsT[i * 65 + s];
    const float4* w4 = (const float4*)(VdT + i * 128 + kq * 32);
    #pragma unroll
    for (int g = 0; g < 8; ++g) {
      float4 w = w4[g];
      acc[g].x += e * w.x; acc[g].y += e * w.y; acc[g].z += e * w.z; acc[g].w += e * w.w;
    }
  }
  unsigned short* outp = AET + (size_t)b * 8192;
  #pragma unroll
  for (int g = 0; g < 4; ++g) {
    float4 a0 = acc[2 * g], a1 = acc[2 * g + 1];
    uint4 pk;
    pk.x = pack_bf(a0.x, a0.y); pk.y = pack_bf(a0.z, a0.w);
    pk.z = pack_bf(a1.x, a1.y); pk.w = pack_bf(a1.z, a1.w);
    *(uint4*)(outp + (size_t)(kq * 4 + g) * 512 + s * 8) = pk;
  }
}

// ---------------------------------------------------------------- decoder init: pvsG + ad0 (MFMA)
__global__ __launch_bounds__(256) void init_dec_kernel(
    const float* __restrict__ x_in,
    const unsigned short* __restrict__ dG, const float* __restrict__ cG,
    const unsigned short* __restrict__ WdTm,
    const float* __restrict__ smean_g, const float* __restrict__ sstd_g,
    const float* __restrict__ pmean_g,
    unsigned short* __restrict__ adG, float* __restrict__ pvsG) {
  __shared__ unsigned short dcB[16 * 264];
  const int tid = threadIdx.x;
  const int b0 = blockIdx.x * 16;
  const int l = tid & 63, w = tid >> 6;
  const int quad = l >> 4, l15 = l & 15;

  {
    int m = tid >> 4, i0 = (tid & 15) * 8;
    *(uint4*)&dcB[m * 264 + i0] = *(const uint4*)(dG + (size_t)(b0 + m) * 128 + i0);
    float4 c0 = *(const float4*)(cG + (size_t)(b0 + m) * 128 + i0);
    float4 c1 = *(const float4*)(cG + (size_t)(b0 + m) * 128 + i0 + 4);
    uint4 pk;
    pk.x = pack_bf(c0.x, c0.y); pk.y = pack_bf(c0.z, c0.w);
    pk.z = pack_bf(c1.x, c1.y); pk.w = pack_bf(c1.z, c1.w);
    *(uint4*)&dcB[m * 264 + 128 + i0] = pk;
  }
  if (tid < 48) {
    int m = tid / 3, jj = tid % 3;
    const float* xi = x_in + (size_t)(b0 + m) * 576;
    float sm = smean_g[jj], ss = sstd_g[jj], pm = pmean_g[jj];
    float v  = xi[63 * 9 + 3 + jj] * ss + sm;
    float pv = xi[62 * 9 + 3 + jj] * ss + sm;
    float* P = pvsG + (size_t)(b0 + m) * 12;
    P[jj] = xi[63 * 9 + jj] + pm;
    P[3 + jj] = v;
    P[6 + jj] = (v - pv) / DT_;
  }
  __syncthreads();
  #pragma unroll
  for (int t = 0; t < 2; ++t) {
    const int nt = w + 4 * t;
    f32x4 acc = {0.f, 0.f, 0.f, 0.f};
    #pragma unroll
    for (int ks = 0; ks < 8; ++ks) {
      uint4 au = *(const uint4*)&dcB[l15 * 264 + ks * 32 + quad * 8];
      uint4 bu = *(const uint4*)(WdTm + (size_t)((ks * 8 + nt) * 64 + l) * 8);
      acc = __builtin_amdgcn_mfma_f32_16x16x32_bf16(
          __builtin_bit_cast(bf16x8, au), __builtin_bit_cast(bf16x8, bu), acc, 0, 0, 0);
    }
    int n = nt * 16 + l15;
    #pragma unroll
    for (int r = 0; r < 4; ++r)
      adG[(size_t)(b0 + quad * 4 + r) * 128 + n] = f2bfu(acc[r]);
  }
}

// ---------------------------------------------------------------- per-step attention (streaming)
__global__ __launch_bounds__(256, 8) void attn_step_kernel(
    const unsigned short* __restrict__ AET, const unsigned short* __restrict__ EH,
    const unsigned short* __restrict__ adG, const float* __restrict__ v_d_g,
    unsigned short* __restrict__ ctxG) {
  __shared__ unsigned short adL[2 * 128];
  __shared__ float vdL[128];
  __shared__ float scp[2][2][64];
  __shared__ float bet[2][64];
  __shared__ float ctxP[2][2][128];

  const int tid = threadIdx.x;
  const int b0 = blockIdx.x * 2;
  const int l = tid & 63, w = tid >> 6;
  const int ml = w >> 1, half = w & 1;
  const int quad = l >> 4, l15 = l & 15;

  if (tid < 32)
    *(uint4*)&adL[tid * 8] = *(const uint4*)(adG + (size_t)(b0 + (tid >> 4)) * 128 + (tid & 15) * 8);
  if (tid < 128) vdL[tid] = v_d_g[tid];
  __syncthreads();

  {
    const unsigned short* aet = AET + (size_t)(b0 + ml) * 8192 + (size_t)half * 8 * 512;
    const unsigned short* adp = adL + ml * 128 + half * 64;
    float e = 0.f;
    #pragma unroll
    for (int kb = 0; kb < 8; ++kb) {
      uint4 av  = *(const uint4*)(aet + kb * 512 + l * 8);
      uint4 ad8 = *(const uint4*)(adp + kb * 8);
      float4 v0 = *(const float4*)&vdL[half * 64 + kb * 8];
      float4 v1 = *(const float4*)&vdL[half * 64 + kb * 8 + 4];
      e += fast_tanh(bf_lo(ad8.x) + bf_lo(av.x)) * v0.x;
      e += fast_tanh(bf_hi(ad8.x) + bf_hi(av.x)) * v0.y;
      e += fast_tanh(bf_lo(ad8.y) + bf_lo(av.y)) * v0.z;
      e += fast_tanh(bf_hi(ad8.y) + bf_hi(av.y)) * v0.w;
      e += fast_tanh(bf_lo(ad8.z) + bf_lo(av.z)) * v1.x;
      e += fast_tanh(bf_hi(ad8.z) + bf_hi(av.z)) * v1.y;
      e += fast_tanh(bf_lo(ad8.w) + bf_lo(av.w)) * v1.z;
      e += fast_tanh(bf_hi(ad8.w) + bf_hi(av.w)) * v1.w;
    }
    scp[ml][half][l] = e;
  }
  __syncthreads();
  if (half == 0) {
    float e = scp[ml][0][l] + scp[ml][1][l];
    float mx = e;
    #pragma unroll
    for (int off = 32; off; off >>= 1) mx = fmaxf(mx, __shfl_xor(mx, off, 64));
    float ex = __expf(e - mx);
    float ss = ex;
    #pragma unroll
    for (int off = 32; off; off >>= 1) ss += __shfl_xor(ss, off, 64);
    bet[ml][l] = __fdividef(ex, ss);
  }
  __syncthreads();
  {
    const unsigned short* base = EH + (size_t)(b0 + ml) * 8192 + (size_t)half * 32 * 128;
    float a[8];
    #pragma unroll
    for (int r = 0; r < 8; ++r) a[r] = 0.f;
    #pragma unroll
    for (int it = 0; it < 8; ++it) {
      int sl = it * 4 + quad;
      uint4 ev = *(const uint4*)(base + sl * 128 + l15 * 8);
      float bt = bet[ml][half * 32 + sl];
      a[0] += bt * bf_lo(ev.x); a[1] += bt * bf_hi(ev.x);
      a[2] += bt * bf_lo(ev.y); a[3] += bt * bf_hi(ev.y);
      a[4] += bt * bf_lo(ev.z); a[5] += bt * bf_hi(ev.z);
      a[6] += bt * bf_lo(ev.w); a[7] += bt * bf_hi(ev.w);
    }
    #pragma unroll
    for (int r = 0; r < 8; ++r) {
      a[r] += __shfl_xor(a[r], 16, 64);
      a[r] += __shfl_xor(a[r], 32, 64);
    }
    if (quad == 0) {
      *(float4*)&ctxP[ml][half][l15 * 8]     = make_float4(a[0], a[1], a[2], a[3]);
      *(float4*)&ctxP[ml][half][l15 * 8 + 4] = make_float4(a[4], a[5], a[6], a[7]);
    }
  }
  __syncthreads();
  if (tid < 128) {
    int mi = tid >> 6, hp = (tid & 63) * 2;
    float c0 = ctxP[mi][0][hp]     + ctxP[mi][1][hp];
    float c1 = ctxP[mi][0][hp + 1] + ctxP[mi][1][hp + 1];
    *(unsigned int*)(ctxG + (size_t)(b0 + mi) * 128 + hp) = pack_bf(c0, c1);
  }
}

// ---------------------------------------------------------------- per-step GEMM: gates+LSTM+out+next ad
__global__ __launch_bounds__(512, 2) void gemm_step_kernel(
    const float* __restrict__ ws,
    const unsigned short* __restrict__ dG_in, float* __restrict__ cG,
    const unsigned short* __restrict__ ctxG,
    const unsigned short* __restrict__ WdTm, const unsigned short* __restrict__ WdecTm,
    unsigned short* __restrict__ dG_out, unsigned short* __restrict__ adG,
    float* __restrict__ pvsG,
    const float* __restrict__ b_out_g, const float* __restrict__ smean_g,
    const float* __restrict__ sstd_g, const float* __restrict__ pmean_g,
    float* __restrict__ out, int hz) {
  __shared__ unsigned short gA[16 * 296];
  __shared__ unsigned short dcB[16 * 264];
  __shared__ float pd[16 * 3 * 8];
  __shared__ float pc[16 * 3 * 4];

  const int tid = threadIdx.x;
  const int b0 = blockIdx.x * 16;
  const int l = tid & 63, w = tid >> 6;
  const int quad = l >> 4, l15 = l & 15;

  if (tid < 256) {
    int m = tid >> 4, i0 = (tid & 15) * 8;
    *(uint4*)&gA[m * 296 + i0] = *(const uint4*)(dG_in + (size_t)(b0 + m) * 128 + i0);
  } else {
    int t = tid - 256;
    int m = t >> 4, i0 = (t & 15) * 8;
    *(uint4*)&gA[m * 296 + 128 + i0] = *(const uint4*)(ctxG + (size_t)(b0 + m) * 128 + i0);
  }
  if (tid < 496) { int mm = tid / 31, r = tid % 31; gA[mm * 296 + 265 + r] = 0; }
  if (tid < 48) {
    int m = tid / 3, jj = tid % 3;
    const float* P = pvsG + (size_t)(b0 + m) * 12;
    float sm = smean_g[jj], ss = sstd_g[jj], pm = pmean_g[jj];
    gA[m * 296 + 256 + jj]     = f2bfu(P[jj] - pm);
    gA[m * 296 + 256 + 3 + jj] = f2bfu((P[3 + jj] - sm) / ss);
    gA[m * 296 + 256 + 6 + jj] = f2bfu(P[6 + jj] / ss);
  }
  __syncthreads();

  {
    uint4 af[9];
    #pragma unroll
    for (int ks = 0; ks < 9; ++ks)
      af[ks] = *(const uint4*)&gA[l15 * 296 + ks * 32 + quad * 8];
    const int is = w, i = is * 16 + l15;
    float bb[4], wd[3];
    #pragma unroll
    for (int q = 0; q < 4; ++q) bb[q] = ws[OFF_BDEC + q * 128 + i];
    #pragma unroll
    for (int jj = 0; jj < 3; ++jj) wd[jj] = ws[OFF_WOUTT + i * 3 + jj];
    f32x4 g4[4];
    #pragma unroll
    for (int q = 0; q < 4; ++q) {
      f32x4 acc = {0.f, 0.f, 0.f, 0.f};
      #pragma unroll
      for (int ks = 0; ks < 9; ++ks) {
        uint4 bu = *(const uint4*)(WdecTm + (size_t)(((is * 4 + q) * 9 + ks) * 64 + l) * 8);
        acc = __builtin_amdgcn_mfma_f32_16x16x32_bf16(
            __builtin_bit_cast(bf16x8, af[ks]), __builtin_bit_cast(bf16x8, bu), acc, 0, 0, 0);
      }
      g4[q] = acc;
    }
    float pr[4][3];
    #pragma unroll
    for (int r = 0; r < 4; ++r) {
      int m = quad * 4 + r;
      float gi = g4[0][r] + bb[0];
      float gf = g4[1][r] + bb[1];
      float gg = g4[2][r] + bb[2];
      float go = g4[3][r] + bb[3];
      float co = cG[(size_t)(b0 + m) * 128 + i];
      float cn = sigf(gf) * co + sigf(gi) * fast_tanh(gg);
      float hn = sigf(go) * fast_tanh(cn);
      cG[(size_t)(b0 + m) * 128 + i] = cn;
      unsigned short hb = f2bfu(hn);
      dG_out[(size_t)(b0 + m) * 128 + i] = hb;
      dcB[m * 264 + i] = hb;
      dcB[m * 264 + 128 + i] = f2bfu(cn);
      pr[r][0] = hn * wd[0]; pr[r][1] = hn * wd[1]; pr[r][2] = hn * wd[2];
    }
    #pragma unroll
    for (int r = 0; r < 4; ++r)
      #pragma unroll
      for (int jj = 0; jj < 3; ++jj) {
        float v = pr[r][jj];
        #pragma unroll
        for (int off = 8; off; off >>= 1) v += __shfl_xor(v, off, 64);
        pr[r][jj] = v;
      }
    if (l15 == 0) {
      #pragma unroll
      for (int r = 0; r < 4; ++r)
        #pragma unroll
        for (int jj = 0; jj < 3; ++jj)
          pd[((quad * 4 + r) * 3 + jj) * 8 + is] = pr[r][jj];
    }
  }
  __syncthreads();

  {
    const int nt = w;
    f32x4 acc = {0.f, 0.f, 0.f, 0.f};
    #pragma unroll
    for (int ks = 0; ks < 8; ++ks) {
      uint4 au = *(const uint4*)&dcB[l15 * 264 + ks * 32 + quad * 8];
      uint4 bu = *(const uint4*)(WdTm + (size_t)((ks * 8 + nt) * 64 + l) * 8);
      acc = __builtin_amdgcn_mfma_f32_16x16x32_bf16(
          __builtin_bit_cast(bf16x8, au), __builtin_bit_cast(bf16x8, bu), acc, 0, 0, 0);
    }
    int n = nt * 16 + l15;
    #pragma unroll
    for (int r = 0; r < 4; ++r) {
      int m = quad * 4 + r;
      adG[(size_t)(b0 + m) * 128 + n] = f2bfu(acc[r]);
    }
  }
  if (tid < 192) {
    int m = tid / 12, jj = (tid % 12) / 4, part = tid % 4;
    int k0 = part * 32;
    float acc = 0.f;
    for (int k = k0; k < k0 + 32; ++k) {
      __hip_bfloat16 hv = *(__hip_bfloat16*)&gA[m * 296 + 128 + k];
      acc += __bfloat162float(hv) * ws[OFF_WOUTT + 384 + k * 3 + jj];
    }
    pc[(m * 3 + jj) * 4 + part] = acc;
  }
  __syncthreads();

  if (tid < 48) {
    int m = tid / 3, jj = tid % 3;
    float s = b_out_g[jj];
    #pragma unroll
    for (int p = 0; p < 4; ++p) s += pc[(m * 3 + jj) * 4 + p];
    #pragma unroll
    for (int is = 0; is < 8; ++is) s += pd[(m * 3 + jj) * 8 + is];
    float pacc = s * sstd_g[jj];
    float* P = pvsG + (size_t)(b0 + m) * 12;
    float pos = P[jj], vel = P[3 + jj], acc = P[6 + jj];
    float ppred = pos + vel * DT_ + 0.5f * acc * DT_ * DT_;
    float vnew  = vel + 0.5f * (acc + pacc) * DT_;
    size_t ob = ((size_t)(b0 + m) * HZ_ + hz) * 9;
    out[ob + jj] = ppred; out[ob + 3 + jj] = vnew; out[ob + 6 + jj] = pacc;
    P[jj] = ppred; P[3 + jj] = vnew; P[6 + jj] = pacc;
  }
}

// ---------------------------------------------------------------- launch
extern "C" void kernel_launch(void* const* d_in, const int* in_sizes, int n_in,
                              void* d_out, int out_size, void* d_ws, size_t ws_size,
                              hipStream_t stream) {
  (void)in_sizes; (void)n_in; (void)out_size; (void)ws_size;
  const float* x      = (const float*)d_in[0];
  const float* Wih_e  = (const float*)d_in[1];
  const float* Whh_e  = (const float*)d_in[2];
  const float* bih_e  = (const float*)d_in[3];
  const float* bhh_e  = (const float*)d_in[4];
  const float* W_e    = (const float*)d_in[5];
  const float* V_e    = (const float*)d_in[6];
  const float* v_e    = (const float*)d_in[7];
  const float* W_d    = (const float*)d_in[8];
  const float* V_d    = (const float*)d_in[9];
  const float* v_d    = (const float*)d_in[10];
  const float* Wih_d  = (const float*)d_in[11];
  const float* Whh_d  = (const float*)d_in[12];
  const float* bih_d  = (const float*)d_in[13];
  const float* bhh_d  = (const float*)d_in[14];
  const float* W_out  = (const float*)d_in[15];
  const float* b_out  = (const float*)d_in[16];
  const float* smean  = (const float*)d_in[17];
  const float* sstd   = (const float*)d_in[18];
  const float* pmean  = (const float*)d_in[19];

  float* ws = (float*)d_ws;
  float* pvsG = ws;                                           // over dead encoder tables
  unsigned short* WeTm   = (unsigned short*)(ws + OFF_WET);
  unsigned short* WencTm = (unsigned short*)(ws + OFF_WENCT);
  unsigned short* WdTm   = (unsigned short*)(ws + OFF_WDT);
  unsigned short* WdecTm = (unsigned short*)(ws + OFF_WDECT);
  unsigned short* dG     = (unsigned short*)(ws + OFF_DECD);
  unsigned short* ctxG   = dG + 524288;
  float* cG = ws + OFF_DECC;
  unsigned short* ub  = (unsigned short*)(ws + F32_TOTAL);
  unsigned short* EH  = ub;
  unsigned short* AET = ub + 33554432;
  unsigned short* adG = ub + 67108864;
  float* out = (float*)d_out;

  prep_kernel<<<(PREP_N + 255) / 256, 256, 0, stream>>>(
      Wih_e, Whh_e, bih_e, bhh_e, W_e, V_e, W_d, V_d,
      Wih_d, Whh_d, bih_d, bhh_d, W_out, ws);
  prep_mfma_kernel<<<(32768 + 147456 + 255) / 256, 256, 0, stream>>>(
      W_d, Wih_d, Whh_d, WdTm, WdecTm);
  prep_enc_mfma_kernel<<<(16384 + 81920 + 255) / 256, 256, 0, stream>>>(
      W_e, Wih_e, Whh_e, WeTm, WencTm);
  encoder_mfma_kernel<<<B_ / 16, 512, 0, stream>>>(
      x, ws, v_e, WeTm, WencTm, (__hip_bfloat16*)EH, dG, cG);
  attnenc_t_kernel<<<B_, 256, 0, stream>>>(ws, (const __hip_bfloat16*)EH, AET);
  init_dec_kernel<<<B_ / 16, 256, 0, stream>>>(
      x, dG, cG, WdTm, smean, sstd, pmean, adG, pvsG);
  for (int hz = 0; hz < HZ_; ++hz) {
    attn_step_kernel<<<B_ / 2, 256, 0, stream>>>(AET, EH, adG, v_d, ctxG);
    gemm_step_kernel<<<B_ / 16, 512, 0, stream>>>(
        ws, dG, cG, ctxG, WdTm, WdecTm, dG, adG, pvsG,
        b_out, smean, sstd, pmean, out, hz);
  }
}

// Round 8
// 1833.171 us; speedup vs baseline: 8.2860x; 1.2785x over previous
//
#include <hip/hip_runtime.h>
#include <hip/hip_bf16.h>

// Problem constants
#define B_   4096
#define S_   64
#define D_   9
#define H_   128
#define HZ_  32
#define DT_  0.1f

// f32 region layout (float offsets). Regions overlap in TIME, never within a kernel.
#define OFF_WET    0          // slot hosts WeTm  (bf16, 16384 ush) [encoder only]
#define OFF_VET    16384      // 4096 f32 V_e^T   [encoder only]
#define OFF_WENCT  20480      // slot hosts WencTm (bf16, 81920 ush) [encoder only]
#define OFF_BENC   90624      // 512   [encoder only]
#define OFF_WDT    91136      // slot hosts WdTm (bf16, 32768 ush)
#define OFF_WDECT  123904     // slot hosts WdecTm (bf16, 147456 ush)
#define OFF_BDEC   259584     // 512   (live, gemm)
#define OFF_WOUTT  260096     // 768   (live, gemm)
#define OFF_VDT    260864     // slot hosts VdTm (bf16, 16384 ush) [attnenc MFMA B-frags]
#define OFF_DECD   277248     // slot hosts dG (524288 ush) + ctxG (524288 ush)
#define OFF_DECC   801536     // 524288 : live c-state f32 (cG)
#define F32_TOTAL  1325824
#define PREP_N     277248

// ushort region after f32 region: EH (33554432) | AET (33554432) | adG (524288)

typedef __bf16 bf16x8 __attribute__((ext_vector_type(8)));
typedef float  f32x4  __attribute__((ext_vector_type(4)));

__device__ __forceinline__ float fast_tanh(float x) {
    float e = __expf(2.0f * x);
    return 1.0f - __fdividef(2.0f, e + 1.0f);
}
__device__ __forceinline__ float sigf(float x) {
    return __fdividef(1.0f, 1.0f + __expf(-x));
}
__device__ __forceinline__ float bf_lo(unsigned int u) { return __uint_as_float(u << 16); }
__device__ __forceinline__ float bf_hi(unsigned int u) { return __uint_as_float(u & 0xffff0000u); }
__device__ __forceinline__ unsigned short f2bfu(float f) {
    __hip_bfloat16 b = __float2bfloat16(f);
    return *(unsigned short*)&b;
}
__device__ __forceinline__ unsigned int pack_bf(float lo, float hi) {
    return (unsigned int)f2bfu(lo) | ((unsigned int)f2bfu(hi) << 16);
}

// ---------------------------------------------------------------- prep (f32 tables)
__global__ void prep_kernel(const float* __restrict__ Wih_e, const float* __restrict__ Whh_e,
    const float* __restrict__ bih_e, const float* __restrict__ bhh_e,
    const float* __restrict__ W_e, const float* __restrict__ V_e,
    const float* __restrict__ W_d, const float* __restrict__ V_d,
    const float* __restrict__ Wih_d, const float* __restrict__ Whh_d,
    const float* __restrict__ bih_d, const float* __restrict__ bhh_d,
    const float* __restrict__ W_out, float* __restrict__ ws) {
  for (int idx = blockIdx.x * blockDim.x + threadIdx.x; idx < PREP_N;
       idx += gridDim.x * blockDim.x) {
    int i = idx;
    if (i < 16384) { continue; }   // WET slot -> WeTm (prep_enc_mfma)
    i -= 16384;
    if (i < 4096) { int s = i >> 6, t = i & 63; ws[OFF_VET + i] = V_e[t * 64 + s]; continue; }
    i -= 4096;
    if (i < 70144) { continue; }   // WENCT slot -> WencTm (prep_enc_mfma)
    i -= 70144;
    if (i < 512) { ws[OFF_BENC + i] = bih_e[i] + bhh_e[i]; continue; }
    i -= 512;
    if (i < 32768) { continue; }   // WDT slot -> WdTm
    i -= 32768;
    if (i < 135680) { continue; }  // WDECT slot -> WdecTm
    i -= 135680;
    if (i < 512) { ws[OFF_BDEC + i] = bih_d[i] + bhh_d[i]; continue; }
    i -= 512;
    if (i < 768) { int k = i / 3, j = i % 3; ws[OFF_WOUTT + i] = W_out[j * 256 + k]; continue; }
    // remaining range (old VDT f32) — now hosts VdTm bf16 from prep_enc_mfma; nothing to do
  }
}

// ---------------------------------------------------------------- prep decoder MFMA weights
__global__ void prep_mfma_kernel(const float* __restrict__ W_d,
    const float* __restrict__ Wih_d, const float* __restrict__ Whh_d,
    unsigned short* __restrict__ WdTm, unsigned short* __restrict__ WdecTm) {
  int idx = blockIdx.x * blockDim.x + threadIdx.x;
  if (idx < 32768) {
    int j = idx & 7, l = (idx >> 3) & 63, t = idx >> 9;
    int nt = t & 7, ks = t >> 3;
    int k = ks * 32 + (l >> 4) * 8 + j;
    int n = nt * 16 + (l & 15);
    WdTm[idx] = f2bfu(W_d[n * 256 + k]);
    return;
  }
  int i2 = idx - 32768;
  if (i2 < 147456) {
    int j = i2 & 7, l = (i2 >> 3) & 63, t = i2 >> 9;   // t in [0,288)
    int ks = t % 9, tile = t / 9;
    int q = tile & 3, is = tile >> 2;
    int k = ks * 32 + (l >> 4) * 8 + j;
    int g = q * 128 + is * 16 + (l & 15);
    float v;
    if (k < 128)      v = Whh_d[g * 128 + k];
    else if (k < 256) v = Wih_d[g * 137 + 9 + (k - 128)];
    else if (k < 265) v = Wih_d[g * 137 + (k - 256)];
    else              v = 0.f;
    WdecTm[i2] = f2bfu(v);
  }
}

// ---------------------------------------------------------------- prep encoder MFMA weights + VdTm
// WeTm  : tiles (ks 0..7, nt 0..3): n=nt*16+l15 (s), k=ks*32+(l>>4)*8+j over [h;c]; val=W_e[n][k]
// WencTm: tiles (is 0..7, q 0..3, ks 0..4): i=is*16+l15, g=q*128+i
// VdTm  : tiles (ks 0..3, nt 0..7): n(col)=nt*16+l15 (k of V_d), kdim i=ks*32+(l>>4)*8+j; val=V_d[n][i]
__global__ void prep_enc_mfma_kernel(const float* __restrict__ W_e,
    const float* __restrict__ Wih_e, const float* __restrict__ Whh_e,
    const float* __restrict__ V_d,
    unsigned short* __restrict__ WeTm, unsigned short* __restrict__ WencTm,
    unsigned short* __restrict__ VdTm) {
  int idx = blockIdx.x * blockDim.x + threadIdx.x;
  if (idx < 16384) {
    int j = idx & 7, l = (idx >> 3) & 63, tile = idx >> 9;  // ks*4+nt
    int nt = tile & 3, ks = tile >> 2;
    int k = ks * 32 + (l >> 4) * 8 + j;
    int n = nt * 16 + (l & 15);
    WeTm[idx] = f2bfu(W_e[n * 256 + k]);
    return;
  }
  int i2 = idx - 16384;
  if (i2 < 81920) {
    int j = i2 & 7, l = (i2 >> 3) & 63, tile = i2 >> 9;  // (is*4+q)*5+ks
    int ks = tile % 5, tq = tile / 5;
    int q = tq & 3, is = tq >> 2;
    int kk = (l >> 4) * 8 + j;
    int g = q * 128 + is * 16 + (l & 15);
    float v;
    if (ks < 4) v = Whh_e[g * 128 + ks * 32 + kk];
    else        v = (kk < 9) ? Wih_e[g * 9 + kk] : 0.f;
    WencTm[i2] = f2bfu(v);
    return;
  }
  int i3 = i2 - 81920;
  if (i3 < 16384) {
    int j = i3 & 7, l = (i3 >> 3) & 63, tile = i3 >> 9;  // ks*8+nt
    int nt = tile & 7, ks = tile >> 3;
    int i = ks * 32 + (l >> 4) * 8 + j;
    int n = nt * 16 + (l & 15);
    VdTm[i3] = f2bfu(V_d[n * 128 + i]);
  }
}

// ---------------------------------------------------------------- encoder (MFMA, 16 batches, 512 thr)
__global__ __launch_bounds__(512, 1) void encoder_mfma_kernel(
    const float* __restrict__ x_in, const float* __restrict__ ws,
    const float* __restrict__ v_e_g,
    const unsigned short* __restrict__ WeTm, const unsigned short* __restrict__ WencTm,
    __hip_bfloat16* __restrict__ EH,
    unsigned short* __restrict__ dG, float* __restrict__ cG) {
  __shared__ unsigned short hA[2][16 * 296];  // [h 0..127 | c 128..255 | xs 256..264 | zeros..287]
  __shared__ float cF[16 * 132];
  __shared__ float ahL[16 * 64];
  __shared__ float aiL[16 * 576];
  __shared__ float xbL[16 * 576];

  const int tid = threadIdx.x;
  const int b0 = blockIdx.x * 16;
  const int l = tid & 63, w = tid >> 6;     // 8 waves
  const int quad = l >> 4, l15 = l & 15;

  for (int i = tid; i < 16 * 576; i += 512) {
    int m = i / 576, r = i % 576;
    xbL[i] = x_in[(size_t)(b0 + m) * 576 + r];
  }
  for (int i = tid; i < 2 * 16 * 296; i += 512) ((unsigned short*)hA)[i] = 0;
  for (int i = tid; i < 16 * 132; i += 512) cF[i] = 0.f;
  __syncthreads();

  {
    const float* __restrict__ VeT = ws + OFF_VET;
    for (int i = tid; i < 16 * 576; i += 512) {
      int t = i & 63, dd = (i >> 6) % 9, m = i / 576;
      float acc = 0.f;
      for (int s = 0; s < 64; ++s) acc += xbL[m * 576 + s * 9 + dd] * VeT[s * 64 + t];
      aiL[m * 576 + dd * 64 + t] = acc;
    }
  }
  const float ve_r = v_e_g[l];
  const int ig = w * 16 + l15;
  float bbq[4];
  #pragma unroll
  for (int q = 0; q < 4; ++q) bbq[q] = ws[OFF_BENC + q * 128 + ig];
  __syncthreads();

  for (int t = 0; t < S_; ++t) {
    unsigned short* bufC = hA[t & 1];
    unsigned short* bufN = hA[(t + 1) & 1];
    if (w < 4) {
      f32x4 acc = {0.f, 0.f, 0.f, 0.f};
      #pragma unroll
      for (int ks = 0; ks < 8; ++ks) {
        uint4 au = *(const uint4*)&bufC[l15 * 296 + ks * 32 + quad * 8];
        uint4 bu = *(const uint4*)(WeTm + (size_t)((ks * 4 + w) * 64 + l) * 8);
        acc = __builtin_amdgcn_mfma_f32_16x16x32_bf16(
            __builtin_bit_cast(bf16x8, au), __builtin_bit_cast(bf16x8, bu), acc, 0, 0, 0);
      }
      #pragma unroll
      for (int r = 0; r < 4; ++r)
        ahL[(quad * 4 + r) * 64 + w * 16 + l15] = acc[r];
    }
    __syncthreads();
    {
      const int m0 = 2 * w, m1 = 2 * w + 1;
      float a0 = ahL[m0 * 64 + l], a1 = ahL[m1 * 64 + l];
      float e0k = -1e30f, e1k = -1e30f;
      #pragma unroll
      for (int dd = 0; dd < 9; ++dd) {
        float t0 = fast_tanh(a0 + aiL[m0 * 576 + dd * 64 + l]) * ve_r;
        float t1 = fast_tanh(a1 + aiL[m1 * 576 + dd * 64 + l]) * ve_r;
        #pragma unroll
        for (int off = 32; off; off >>= 1) {
          t0 += __shfl_xor(t0, off, 64);
          t1 += __shfl_xor(t1, off, 64);
        }
        if (l == dd) { e0k = t0; e1k = t1; }
      }
      float mx0 = e0k, mx1 = e1k;
      #pragma unroll
      for (int off = 8; off; off >>= 1) {
        mx0 = fmaxf(mx0, __shfl_xor(mx0, off, 64));
        mx1 = fmaxf(mx1, __shfl_xor(mx1, off, 64));
      }
      float ex0 = (l < 9) ? __expf(e0k - mx0) : 0.f;
      float ex1 = (l < 9) ? __expf(e1k - mx1) : 0.f;
      float s0 = ex0, s1 = ex1;
      #pragma unroll
      for (int off = 8; off; off >>= 1) {
        s0 += __shfl_xor(s0, off, 64);
        s1 += __shfl_xor(s1, off, 64);
      }
      if (l < 9) {
        bufC[m0 * 296 + 256 + l] = f2bfu(__fdividef(ex0, s0) * xbL[m0 * 576 + t * 9 + l]);
        bufC[m1 * 296 + 256 + l] = f2bfu(__fdividef(ex1, s1) * xbL[m1 * 576 + t * 9 + l]);
      }
    }
    __syncthreads();
    {
      uint4 af[5];
      #pragma unroll
      for (int ks = 0; ks < 4; ++ks)
        af[ks] = *(const uint4*)&bufC[l15 * 296 + ks * 32 + quad * 8];
      af[4] = *(const uint4*)&bufC[l15 * 296 + 256 + quad * 8];
      f32x4 g4[4];
      #pragma unroll
      for (int q = 0; q < 4; ++q) {
        f32x4 acc = {0.f, 0.f, 0.f, 0.f};
        #pragma unroll
        for (int ks = 0; ks < 5; ++ks) {
          uint4 bu = *(const uint4*)(WencTm + (size_t)(((w * 4 + q) * 5 + ks) * 64 + l) * 8);
          acc = __builtin_amdgcn_mfma_f32_16x16x32_bf16(
              __builtin_bit_cast(bf16x8, af[ks]), __builtin_bit_cast(bf16x8, bu), acc, 0, 0, 0);
        }
        g4[q] = acc;
      }
      #pragma unroll
      for (int r = 0; r < 4; ++r) {
        int m = quad * 4 + r;
        float gi = g4[0][r] + bbq[0];
        float gf = g4[1][r] + bbq[1];
        float gg = g4[2][r] + bbq[2];
        float go = g4[3][r] + bbq[3];
        float co = cF[m * 132 + ig];
        float cn = sigf(gf) * co + sigf(gi) * fast_tanh(gg);
        float hn = sigf(go) * fast_tanh(cn);
        cF[m * 132 + ig] = cn;
        bufN[m * 296 + ig] = f2bfu(hn);
        bufN[m * 296 + 128 + ig] = f2bfu(cn);
        EH[((size_t)(b0 + m) * S_ + t) * H_ + ig] = __float2bfloat16(hn);
      }
    }
    __syncthreads();
  }
  for (int i = tid; i < 16 * 128; i += 512) {
    int m = i >> 7, ii = i & 127;
    dG[(size_t)(b0 + m) * 128 + ii] = hA[0][m * 296 + ii];
    cG[(size_t)(b0 + m) * 128 + ii] = cF[m * 132 + ii];
  }
}

// ---------------------------------------------------------------- attn_encoder^T via MFMA
// out[(b,s)][k] = sum_i EH[b,s,i] * V_d[k][i].  1024 blocks x 4 waves; wave = one batch.
// A-frags register-resident (16 uint4), B = VdTm (32 KB, L2). Direct k-packed AET stores.
__global__ __launch_bounds__(256) void attnenc_mfma_kernel(
    const unsigned short* __restrict__ EH, const unsigned short* __restrict__ VdTm,
    unsigned short* __restrict__ AET) {
  const int tid = threadIdx.x;
  const int b = blockIdx.x * 4 + (tid >> 6);
  const int l = tid & 63;
  const int quad = l >> 4, l15 = l & 15;

  const unsigned short* ehb = EH + (size_t)b * 8192;
  uint4 A[4][4];   // [st][ks] : rows s = st*16+l15, kdim i = ks*32+quad*8..+8
  #pragma unroll
  for (int st = 0; st < 4; ++st)
    #pragma unroll
    for (int ks = 0; ks < 4; ++ks)
      A[st][ks] = *(const uint4*)(ehb + (st * 16 + l15) * 128 + ks * 32 + quad * 8);

  unsigned short* outb = AET + (size_t)b * 8192;
  const int k = l15;   // col within tile; global k = nt*16 + l15
  #pragma unroll
  for (int nt = 0; nt < 8; ++nt) {
    uint4 Bf[4];
    #pragma unroll
    for (int ks = 0; ks < 4; ++ks)
      Bf[ks] = *(const uint4*)(VdTm + (size_t)((ks * 8 + nt) * 64 + l) * 8);
    int kg = nt * 16 + k;
    int kb = kg >> 3, k7 = kg & 7;
    #pragma unroll
    for (int st = 0; st < 4; ++st) {
      f32x4 acc = {0.f, 0.f, 0.f, 0.f};
      #pragma unroll
      for (int ks = 0; ks < 4; ++ks)
        acc = __builtin_amdgcn_mfma_f32_16x16x32_bf16(
            __builtin_bit_cast(bf16x8, A[st][ks]), __builtin_bit_cast(bf16x8, Bf[ks]), acc, 0, 0, 0);
      #pragma unroll
      for (int r = 0; r < 4; ++r) {
        int s = st * 16 + quad * 4 + r;
        outb[kb * 512 + s * 8 + k7] = f2bfu(acc[r]);
      }
    }
  }
}

// ---------------------------------------------------------------- decoder init: pvsG + ad0 (MFMA)
__global__ __launch_bounds__(256) void init_dec_kernel(
    const float* __restrict__ x_in,
    const unsigned short* __restrict__ dG, const float* __restrict__ cG,
    const unsigned short* __restrict__ WdTm,
    const float* __restrict__ smean_g, const float* __restrict__ sstd_g,
    const float* __restrict__ pmean_g,
    unsigned short* __restrict__ adG, float* __restrict__ pvsG) {
  __shared__ unsigned short dcB[16 * 264];
  const int tid = threadIdx.x;
  const int b0 = blockIdx.x * 16;
  const int l = tid & 63, w = tid >> 6;
  const int quad = l >> 4, l15 = l & 15;

  {
    int m = tid >> 4, i0 = (tid & 15) * 8;
    *(uint4*)&dcB[m * 264 + i0] = *(const uint4*)(dG + (size_t)(b0 + m) * 128 + i0);
    float4 c0 = *(const float4*)(cG + (size_t)(b0 + m) * 128 + i0);
    float4 c1 = *(const float4*)(cG + (size_t)(b0 + m) * 128 + i0 + 4);
    uint4 pk;
    pk.x = pack_bf(c0.x, c0.y); pk.y = pack_bf(c0.z, c0.w);
    pk.z = pack_bf(c1.x, c1.y); pk.w = pack_bf(c1.z, c1.w);
    *(uint4*)&dcB[m * 264 + 128 + i0] = pk;
  }
  if (tid < 48) {
    int m = tid / 3, jj = tid % 3;
    const float* xi = x_in + (size_t)(b0 + m) * 576;
    float sm = smean_g[jj], ss = sstd_g[jj], pm = pmean_g[jj];
    float v  = xi[63 * 9 + 3 + jj] * ss + sm;
    float pv = xi[62 * 9 + 3 + jj] * ss + sm;
    float* P = pvsG + (size_t)(b0 + m) * 12;
    P[jj] = xi[63 * 9 + jj] + pm;
    P[3 + jj] = v;
    P[6 + jj] = (v - pv) / DT_;
  }
  __syncthreads();
  #pragma unroll
  for (int t = 0; t < 2; ++t) {
    const int nt = w + 4 * t;
    f32x4 acc = {0.f, 0.f, 0.f, 0.f};
    #pragma unroll
    for (int ks = 0; ks < 8; ++ks) {
      uint4 au = *(const uint4*)&dcB[l15 * 264 + ks * 32 + quad * 8];
      uint4 bu = *(const uint4*)(WdTm + (size_t)((ks * 8 + nt) * 64 + l) * 8);
      acc = __builtin_amdgcn_mfma_f32_16x16x32_bf16(
          __builtin_bit_cast(bf16x8, au), __builtin_bit_cast(bf16x8, bu), acc, 0, 0, 0);
    }
    int n = nt * 16 + l15;
    #pragma unroll
    for (int r = 0; r < 4; ++r)
      adG[(size_t)(b0 + quad * 4 + r) * 128 + n] = f2bfu(acc[r]);
  }
}

// ---------------------------------------------------------------- per-step attention (streaming)
__global__ __launch_bounds__(256, 8) void attn_step_kernel(
    const unsigned short* __restrict__ AET, const unsigned short* __restrict__ EH,
    const unsigned short* __restrict__ adG, const float* __restrict__ v_d_g,
    unsigned short* __restrict__ ctxG) {
  __shared__ unsigned short adL[2 * 128];
  __shared__ float vdL[128];
  __shared__ float scp[2][2][64];
  __shared__ float bet[2][64];
  __shared__ float ctxP[2][2][128];

  const int tid = threadIdx.x;
  const int b0 = blockIdx.x * 2;
  const int l = tid & 63, w = tid >> 6;
  const int ml = w >> 1, half = w & 1;
  const int quad = l >> 4, l15 = l & 15;

  if (tid < 32)
    *(uint4*)&adL[tid * 8] = *(const uint4*)(adG + (size_t)(b0 + (tid >> 4)) * 128 + (tid & 15) * 8);
  if (tid < 128) vdL[tid] = v_d_g[tid];
  __syncthreads();

  {
    const unsigned short* aet = AET + (size_t)(b0 + ml) * 8192 + (size_t)half * 8 * 512;
    const unsigned short* adp = adL + ml * 128 + half * 64;
    float e = 0.f;
    #pragma unroll
    for (int kb = 0; kb < 8; ++kb) {
      uint4 av  = *(const uint4*)(aet + kb * 512 + l * 8);
      uint4 ad8 = *(const uint4*)(adp + kb * 8);
      float4 v0 = *(const float4*)&vdL[half * 64 + kb * 8];
      float4 v1 = *(const float4*)&vdL[half * 64 + kb * 8 + 4];
      e += fast_tanh(bf_lo(ad8.x) + bf_lo(av.x)) * v0.x;
      e += fast_tanh(bf_hi(ad8.x) + bf_hi(av.x)) * v0.y;
      e += fast_tanh(bf_lo(ad8.y) + bf_lo(av.y)) * v0.z;
      e += fast_tanh(bf_hi(ad8.y) + bf_hi(av.y)) * v0.w;
      e += fast_tanh(bf_lo(ad8.z) + bf_lo(av.z)) * v1.x;
      e += fast_tanh(bf_hi(ad8.z) + bf_hi(av.z)) * v1.y;
      e += fast_tanh(bf_lo(ad8.w) + bf_lo(av.w)) * v1.z;
      e += fast_tanh(bf_hi(ad8.w) + bf_hi(av.w)) * v1.w;
    }
    scp[ml][half][l] = e;
  }
  __syncthreads();
  if (half == 0) {
    float e = scp[ml][0][l] + scp[ml][1][l];
    float mx = e;
    #pragma unroll
    for (int off = 32; off; off >>= 1) mx = fmaxf(mx, __shfl_xor(mx, off, 64));
    float ex = __expf(e - mx);
    float ss = ex;
    #pragma unroll
    for (int off = 32; off; off >>= 1) ss += __shfl_xor(ss, off, 64);
    bet[ml][l] = __fdividef(ex, ss);
  }
  __syncthreads();
  {
    const unsigned short* base = EH + (size_t)(b0 + ml) * 8192 + (size_t)half * 32 * 128;
    float a[8];
    #pragma unroll
    for (int r = 0; r < 8; ++r) a[r] = 0.f;
    #pragma unroll
    for (int it = 0; it < 8; ++it) {
      int sl = it * 4 + quad;
      uint4 ev = *(const uint4*)(base + sl * 128 + l15 * 8);
      float bt = bet[ml][half * 32 + sl];
      a[0] += bt * bf_lo(ev.x); a[1] += bt * bf_hi(ev.x);
      a[2] += bt * bf_lo(ev.y); a[3] += bt * bf_hi(ev.y);
      a[4] += bt * bf_lo(ev.z); a[5] += bt * bf_hi(ev.z);
      a[6] += bt * bf_lo(ev.w); a[7] += bt * bf_hi(ev.w);
    }
    #pragma unroll
    for (int r = 0; r < 8; ++r) {
      a[r] += __shfl_xor(a[r], 16, 64);
      a[r] += __shfl_xor(a[r], 32, 64);
    }
    if (quad == 0) {
      *(float4*)&ctxP[ml][half][l15 * 8]     = make_float4(a[0], a[1], a[2], a[3]);
      *(float4*)&ctxP[ml][half][l15 * 8 + 4] = make_float4(a[4], a[5], a[6], a[7]);
    }
  }
  __syncthreads();
  if (tid < 128) {
    int mi = tid >> 6, hp = (tid & 63) * 2;
    float c0 = ctxP[mi][0][hp]     + ctxP[mi][1][hp];
    float c1 = ctxP[mi][0][hp + 1] + ctxP[mi][1][hp + 1];
    *(unsigned int*)(ctxG + (size_t)(b0 + mi) * 128 + hp) = pack_bf(c0, c1);
  }
}

// ---------------------------------------------------------------- per-step GEMM: gates+LSTM+out+next ad
__global__ __launch_bounds__(512, 2) void gemm_step_kernel(
    const float* __restrict__ ws,
    const unsigned short* __restrict__ dG_in, float* __restrict__ cG,
    const unsigned short* __restrict__ ctxG,
    const unsigned short* __restrict__ WdTm, const unsigned short* __restrict__ WdecTm,
    unsigned short* __restrict__ dG_out, unsigned short* __restrict__ adG,
    float* __restrict__ pvsG,
    const float* __restrict__ b_out_g, const float* __restrict__ smean_g,
    const float* __restrict__ sstd_g, const float* __restrict__ pmean_g,
    float* __restrict__ out, int hz) {
  __shared__ unsigned short gA[16 * 296];
  __shared__ unsigned short dcB[16 * 264];
  __shared__ float pd[16 * 3 * 8];
  __shared__ float pc[16 * 3 * 4];

  const int tid = threadIdx.x;
  const int b0 = blockIdx.x * 16;
  const int l = tid & 63, w = tid >> 6;
  const int quad = l >> 4, l15 = l & 15;

  if (tid < 256) {
    int m = tid >> 4, i0 = (tid & 15) * 8;
    *(uint4*)&gA[m * 296 + i0] = *(const uint4*)(dG_in + (size_t)(b0 + m) * 128 + i0);
  } else {
    int t = tid - 256;
    int m = t >> 4, i0 = (t & 15) * 8;
    *(uint4*)&gA[m * 296 + 128 + i0] = *(const uint4*)(ctxG + (size_t)(b0 + m) * 128 + i0);
  }
  if (tid < 496) { int mm = tid / 31, r = tid % 31; gA[mm * 296 + 265 + r] = 0; }
  if (tid < 48) {
    int m = tid / 3, jj = tid % 3;
    const float* P = pvsG + (size_t)(b0 + m) * 12;
    float sm = smean_g[jj], ss = sstd_g[jj], pm = pmean_g[jj];
    gA[m * 296 + 256 + jj]     = f2bfu(P[jj] - pm);
    gA[m * 296 + 256 + 3 + jj] = f2bfu((P[3 + jj] - sm) / ss);
    gA[m * 296 + 256 + 6 + jj] = f2bfu(P[6 + jj] / ss);
  }
  __syncthreads();

  {
    uint4 af[9];
    #pragma unroll
    for (int ks = 0; ks < 9; ++ks)
      af[ks] = *(const uint4*)&gA[l15 * 296 + ks * 32 + quad * 8];
    const int is = w, i = is * 16 + l15;
    float bb[4], wd[3];
    #pragma unroll
    for (int q = 0; q < 4; ++q) bb[q] = ws[OFF_BDEC + q * 128 + i];
    #pragma unroll
    for (int jj = 0; jj < 3; ++jj) wd[jj] = ws[OFF_WOUTT + i * 3 + jj];
    f32x4 g4[4];
    #pragma unroll
    for (int q = 0; q < 4; ++q) {
      f32x4 acc = {0.f, 0.f, 0.f, 0.f};
      #pragma unroll
      for (int ks = 0; ks < 9; ++ks) {
        uint4 bu = *(const uint4*)(WdecTm + (size_t)(((is * 4 + q) * 9 + ks) * 64 + l) * 8);
        acc = __builtin_amdgcn_mfma_f32_16x16x32_bf16(
            __builtin_bit_cast(bf16x8, af[ks]), __builtin_bit_cast(bf16x8, bu), acc, 0, 0, 0);
      }
      g4[q] = acc;
    }
    float pr[4][3];
    #pragma unroll
    for (int r = 0; r < 4; ++r) {
      int m = quad * 4 + r;
      float gi = g4[0][r] + bb[0];
      float gf = g4[1][r] + bb[1];
      float gg = g4[2][r] + bb[2];
      float go = g4[3][r] + bb[3];
      float co = cG[(size_t)(b0 + m) * 128 + i];
      float cn = sigf(gf) * co + sigf(gi) * fast_tanh(gg);
      float hn = sigf(go) * fast_tanh(cn);
      cG[(size_t)(b0 + m) * 128 + i] = cn;
      unsigned short hb = f2bfu(hn);
      dG_out[(size_t)(b0 + m) * 128 + i] = hb;
      dcB[m * 264 + i] = hb;
      dcB[m * 264 + 128 + i] = f2bfu(cn);
      pr[r][0] = hn * wd[0]; pr[r][1] = hn * wd[1]; pr[r][2] = hn * wd[2];
    }
    #pragma unroll
    for (int r = 0; r < 4; ++r)
      #pragma unroll
      for (int jj = 0; jj < 3; ++jj) {
        float v = pr[r][jj];
        #pragma unroll
        for (int off = 8; off; off >>= 1) v += __shfl_xor(v, off, 64);
        pr[r][jj] = v;
      }
    if (l15 == 0) {
      #pragma unroll
      for (int r = 0; r < 4; ++r)
        #pragma unroll
        for (int jj = 0; jj < 3; ++jj)
          pd[((quad * 4 + r) * 3 + jj) * 8 + is] = pr[r][jj];
    }
  }
  __syncthreads();

  {
    const int nt = w;
    f32x4 acc = {0.f, 0.f, 0.f, 0.f};
    #pragma unroll
    for (int ks = 0; ks < 8; ++ks) {
      uint4 au = *(const uint4*)&dcB[l15 * 264 + ks * 32 + quad * 8];
      uint4 bu = *(const uint4*)(WdTm + (size_t)((ks * 8 + nt) * 64 + l) * 8);
      acc = __builtin_amdgcn_mfma_f32_16x16x32_bf16(
          __builtin_bit_cast(bf16x8, au), __builtin_bit_cast(bf16x8, bu), acc, 0, 0, 0);
    }
    int n = nt * 16 + l15;
    #pragma unroll
    for (int r = 0; r < 4; ++r) {
      int m = quad * 4 + r;
      adG[(size_t)(b0 + m) * 128 + n] = f2bfu(acc[r]);
    }
  }
  if (tid < 192) {
    int m = tid / 12, jj = (tid % 12) / 4, part = tid % 4;
    int k0 = part * 32;
    float acc = 0.f;
    for (int k = k0; k < k0 + 32; ++k) {
      __hip_bfloat16 hv = *(__hip_bfloat16*)&gA[m * 296 + 128 + k];
      acc += __bfloat162float(hv) * ws[OFF_WOUTT + 384 + k * 3 + jj];
    }
    pc[(m * 3 + jj) * 4 + part] = acc;
  }
  __syncthreads();

  if (tid < 48) {
    int m = tid / 3, jj = tid % 3;
    float s = b_out_g[jj];
    #pragma unroll
    for (int p = 0; p < 4; ++p) s += pc[(m * 3 + jj) * 4 + p];
    #pragma unroll
    for (int is = 0; is < 8; ++is) s += pd[(m * 3 + jj) * 8 + is];
    float pacc = s * sstd_g[jj];
    float* P = pvsG + (size_t)(b0 + m) * 12;
    float pos = P[jj], vel = P[3 + jj], acc = P[6 + jj];
    float ppred = pos + vel * DT_ + 0.5f * acc * DT_ * DT_;
    float vnew  = vel + 0.5f * (acc + pacc) * DT_;
    size_t ob = ((size_t)(b0 + m) * HZ_ + hz) * 9;
    out[ob + jj] = ppred; out[ob + 3 + jj] = vnew; out[ob + 6 + jj] = pacc;
    P[jj] = ppred; P[3 + jj] = vnew; P[6 + jj] = pacc;
  }
}

// ---------------------------------------------------------------- launch
extern "C" void kernel_launch(void* const* d_in, const int* in_sizes, int n_in,
                              void* d_out, int out_size, void* d_ws, size_t ws_size,
                              hipStream_t stream) {
  (void)in_sizes; (void)n_in; (void)out_size; (void)ws_size;
  const float* x      = (const float*)d_in[0];
  const float* Wih_e  = (const float*)d_in[1];
  const float* Whh_e  = (const float*)d_in[2];
  const float* bih_e  = (const float*)d_in[3];
  const float* bhh_e  = (const float*)d_in[4];
  const float* W_e    = (const float*)d_in[5];
  const float* V_e    = (const float*)d_in[6];
  const float* v_e    = (const float*)d_in[7];
  const float* W_d    = (const float*)d_in[8];
  const float* V_d    = (const float*)d_in[9];
  const float* v_d    = (const float*)d_in[10];
  const float* Wih_d  = (const float*)d_in[11];
  const float* Whh_d  = (const float*)d_in[12];
  const float* bih_d  = (const float*)d_in[13];
  const float* bhh_d  = (const float*)d_in[14];
  const float* W_out  = (const float*)d_in[15];
  const float* b_out  = (const float*)d_in[16];
  const float* smean  = (const float*)d_in[17];
  const float* sstd   = (const float*)d_in[18];
  const float* pmean  = (const float*)d_in[19];

  float* ws = (float*)d_ws;
  float* pvsG = ws;                                           // over dead encoder tables
  unsigned short* WeTm   = (unsigned short*)(ws + OFF_WET);
  unsigned short* WencTm = (unsigned short*)(ws + OFF_WENCT);
  unsigned short* WdTm   = (unsigned short*)(ws + OFF_WDT);
  unsigned short* WdecTm = (unsigned short*)(ws + OFF_WDECT);
  unsigned short* VdTm   = (unsigned short*)(ws + OFF_VDT);
  unsigned short* dG     = (unsigned short*)(ws + OFF_DECD);
  unsigned short* ctxG   = dG + 524288;
  float* cG = ws + OFF_DECC;
  unsigned short* ub  = (unsigned short*)(ws + F32_TOTAL);
  unsigned short* EH  = ub;
  unsigned short* AET = ub + 33554432;
  unsigned short* adG = ub + 67108864;
  float* out = (float*)d_out;

  prep_kernel<<<(PREP_N + 255) / 256, 256, 0, stream>>>(
      Wih_e, Whh_e, bih_e, bhh_e, W_e, V_e, W_d, V_d,
      Wih_d, Whh_d, bih_d, bhh_d, W_out, ws);
  prep_mfma_kernel<<<(32768 + 147456 + 255) / 256, 256, 0, stream>>>(
      W_d, Wih_d, Whh_d, WdTm, WdecTm);
  prep_enc_mfma_kernel<<<(16384 + 81920 + 16384 + 255) / 256, 256, 0, stream>>>(
      W_e, Wih_e, Whh_e, V_d, WeTm, WencTm, VdTm);
  encoder_mfma_kernel<<<B_ / 16, 512, 0, stream>>>(
      x, ws, v_e, WeTm, WencTm, (__hip_bfloat16*)EH, dG, cG);
  attnenc_mfma_kernel<<<B_ / 4, 256, 0, stream>>>(EH, VdTm, AET);
  init_dec_kernel<<<B_ / 16, 256, 0, stream>>>(
      x, dG, cG, WdTm, smean, sstd, pmean, adG, pvsG);
  for (int hz = 0; hz < HZ_; ++hz) {
    attn_step_kernel<<<B_ / 2, 256, 0, stream>>>(AET, EH, adG, v_d, ctxG);
    gemm_step_kernel<<<B_ / 16, 512, 0, stream>>>(
        ws, dG, cG, ctxG, WdTm, WdecTm, dG, adG, pvsG,
        b_out, smean, sstd, pmean, out, hz);
  }
}

// Round 9
// 1693.492 us; speedup vs baseline: 8.9694x; 1.0825x over previous
//
#include <hip/hip_runtime.h>
#include <hip/hip_bf16.h>
#include <hip/hip_fp8.h>

// Problem constants
#define B_   4096
#define S_   64
#define D_   9
#define H_   128
#define HZ_  32
#define DT_  0.1f

// f32 region layout (float offsets). Regions overlap in TIME, never within a kernel.
#define OFF_WET    0          // slot hosts WeTm  (bf16, 16384 ush) [encoder only]
#define OFF_VET    16384      // 4096 f32 V_e^T   [encoder only]
#define OFF_WENCT  20480      // slot hosts WencTm (bf16, 81920 ush) [encoder only]
#define OFF_BENC   90624      // 512   [encoder only]
#define OFF_WDT    91136      // slot hosts WdTm (bf16, 32768 ush)
#define OFF_WDECT  123904     // slot hosts WdecTm (bf16, 147456 ush)
#define OFF_BDEC   259584     // 512   (live, gemm)
#define OFF_WOUTT  260096     // 768   (live, gemm)
#define OFF_VDT    260864     // slot hosts VdTm (bf16, 16384 ush) [attnenc MFMA B-frags]
#define OFF_DECD   277248     // slot hosts dG (524288 ush) + ctxG (524288 ush)
#define OFF_DECC   801536     // 524288 : live c-state f32 (cG)
#define F32_TOTAL  1325824
#define PREP_N     277248

// ushort region after f32 region: EH bf16 (33554432 ush) | AETf8 (33.5M bytes) + EHf8 (33.5M bytes)
//   occupying the old AET slot | adG (524288 ush)

typedef __bf16 bf16x8 __attribute__((ext_vector_type(8)));
typedef float  f32x4  __attribute__((ext_vector_type(4)));

__device__ __forceinline__ float fast_tanh(float x) {
    float e = __expf(2.0f * x);
    return 1.0f - __fdividef(2.0f, e + 1.0f);
}
__device__ __forceinline__ float sigf(float x) {
    return __fdividef(1.0f, 1.0f + __expf(-x));
}
__device__ __forceinline__ float bf_lo(unsigned int u) { return __uint_as_float(u << 16); }
__device__ __forceinline__ float bf_hi(unsigned int u) { return __uint_as_float(u & 0xffff0000u); }
__device__ __forceinline__ float bfu2f(unsigned short u) { return __uint_as_float((unsigned int)u << 16); }
__device__ __forceinline__ unsigned short f2bfu(float f) {
    __hip_bfloat16 b = __float2bfloat16(f);
    return *(unsigned short*)&b;
}
__device__ __forceinline__ unsigned int pack_bf(float lo, float hi) {
    return (unsigned int)f2bfu(lo) | ((unsigned int)f2bfu(hi) << 16);
}
__device__ __forceinline__ float f8tof(unsigned int byte) {
    __hip_fp8_e4m3 t; t.__x = (unsigned char)byte; return (float)t;
}
__device__ __forceinline__ unsigned char f2f8(float f) {
    __hip_fp8_e4m3 q(f); return q.__x;
}
__device__ __forceinline__ unsigned int pack4_f8(float a, float b, float c, float d) {
    return (unsigned int)f2f8(a) | ((unsigned int)f2f8(b) << 8) |
           ((unsigned int)f2f8(c) << 16) | ((unsigned int)f2f8(d) << 24);
}

// ---------------------------------------------------------------- prep (f32 tables)
__global__ void prep_kernel(const float* __restrict__ Wih_e, const float* __restrict__ Whh_e,
    const float* __restrict__ bih_e, const float* __restrict__ bhh_e,
    const float* __restrict__ W_e, const float* __restrict__ V_e,
    const float* __restrict__ W_d, const float* __restrict__ V_d,
    const float* __restrict__ Wih_d, const float* __restrict__ Whh_d,
    const float* __restrict__ bih_d, const float* __restrict__ bhh_d,
    const float* __restrict__ W_out, float* __restrict__ ws) {
  for (int idx = blockIdx.x * blockDim.x + threadIdx.x; idx < PREP_N;
       idx += gridDim.x * blockDim.x) {
    int i = idx;
    if (i < 16384) { continue; }
    i -= 16384;
    if (i < 4096) { int s = i >> 6, t = i & 63; ws[OFF_VET + i] = V_e[t * 64 + s]; continue; }
    i -= 4096;
    if (i < 70144) { continue; }
    i -= 70144;
    if (i < 512) { ws[OFF_BENC + i] = bih_e[i] + bhh_e[i]; continue; }
    i -= 512;
    if (i < 32768) { continue; }
    i -= 32768;
    if (i < 135680) { continue; }
    i -= 135680;
    if (i < 512) { ws[OFF_BDEC + i] = bih_d[i] + bhh_d[i]; continue; }
    i -= 512;
    if (i < 768) { int k = i / 3, j = i % 3; ws[OFF_WOUTT + i] = W_out[j * 256 + k]; continue; }
  }
}

// ---------------------------------------------------------------- prep decoder MFMA weights
__global__ void prep_mfma_kernel(const float* __restrict__ W_d,
    const float* __restrict__ Wih_d, const float* __restrict__ Whh_d,
    unsigned short* __restrict__ WdTm, unsigned short* __restrict__ WdecTm) {
  int idx = blockIdx.x * blockDim.x + threadIdx.x;
  if (idx < 32768) {
    int j = idx & 7, l = (idx >> 3) & 63, t = idx >> 9;
    int nt = t & 7, ks = t >> 3;
    int k = ks * 32 + (l >> 4) * 8 + j;
    int n = nt * 16 + (l & 15);
    WdTm[idx] = f2bfu(W_d[n * 256 + k]);
    return;
  }
  int i2 = idx - 32768;
  if (i2 < 147456) {
    int j = i2 & 7, l = (i2 >> 3) & 63, t = i2 >> 9;
    int ks = t % 9, tile = t / 9;
    int q = tile & 3, is = tile >> 2;
    int k = ks * 32 + (l >> 4) * 8 + j;
    int g = q * 128 + is * 16 + (l & 15);
    float v;
    if (k < 128)      v = Whh_d[g * 128 + k];
    else if (k < 256) v = Wih_d[g * 137 + 9 + (k - 128)];
    else if (k < 265) v = Wih_d[g * 137 + (k - 256)];
    else              v = 0.f;
    WdecTm[i2] = f2bfu(v);
  }
}

// ---------------------------------------------------------------- prep encoder MFMA weights + VdTm
__global__ void prep_enc_mfma_kernel(const float* __restrict__ W_e,
    const float* __restrict__ Wih_e, const float* __restrict__ Whh_e,
    const float* __restrict__ V_d,
    unsigned short* __restrict__ WeTm, unsigned short* __restrict__ WencTm,
    unsigned short* __restrict__ VdTm) {
  int idx = blockIdx.x * blockDim.x + threadIdx.x;
  if (idx < 16384) {
    int j = idx & 7, l = (idx >> 3) & 63, tile = idx >> 9;
    int nt = tile & 3, ks = tile >> 2;
    int k = ks * 32 + (l >> 4) * 8 + j;
    int n = nt * 16 + (l & 15);
    WeTm[idx] = f2bfu(W_e[n * 256 + k]);
    return;
  }
  int i2 = idx - 16384;
  if (i2 < 81920) {
    int j = i2 & 7, l = (i2 >> 3) & 63, tile = i2 >> 9;
    int ks = tile % 5, tq = tile / 5;
    int q = tq & 3, is = tq >> 2;
    int kk = (l >> 4) * 8 + j;
    int g = q * 128 + is * 16 + (l & 15);
    float v;
    if (ks < 4) v = Whh_e[g * 128 + ks * 32 + kk];
    else        v = (kk < 9) ? Wih_e[g * 9 + kk] : 0.f;
    WencTm[i2] = f2bfu(v);
    return;
  }
  int i3 = i2 - 81920;
  if (i3 < 16384) {
    int j = i3 & 7, l = (i3 >> 3) & 63, tile = i3 >> 9;
    int nt = tile & 7, ks = tile >> 3;
    int i = ks * 32 + (l >> 4) * 8 + j;
    int n = nt * 16 + (l & 15);
    VdTm[i3] = f2bfu(V_d[n * 128 + i]);
  }
}

// ---------------------------------------------------------------- encoder (MFMA, 16 batches, 512 thr)
// LDS diet: xbL/aiL bf16 -> 68.3 KB total -> 2 blocks/CU (was 105 KB, 1 block/CU).
__global__ __launch_bounds__(512, 1) void encoder_mfma_kernel(
    const float* __restrict__ x_in, const float* __restrict__ ws,
    const float* __restrict__ v_e_g,
    const unsigned short* __restrict__ WeTm, const unsigned short* __restrict__ WencTm,
    __hip_bfloat16* __restrict__ EH,
    unsigned short* __restrict__ dG, float* __restrict__ cG) {
  __shared__ unsigned short hA[2][16 * 296];  // [h | c | xs | zeros]
  __shared__ float cF[16 * 132];
  __shared__ float ahL[16 * 64];
  __shared__ unsigned short aiL[16 * 576];    // bf16
  __shared__ unsigned short xbL[16 * 576];    // bf16

  const int tid = threadIdx.x;
  const int b0 = blockIdx.x * 16;
  const int l = tid & 63, w = tid >> 6;
  const int quad = l >> 4, l15 = l & 15;

  for (int i = tid; i < 16 * 576; i += 512) {
    int m = i / 576, r = i % 576;
    xbL[i] = f2bfu(x_in[(size_t)(b0 + m) * 576 + r]);
  }
  for (int i = tid; i < 2 * 16 * 296; i += 512) ((unsigned short*)hA)[i] = 0;
  for (int i = tid; i < 16 * 132; i += 512) cF[i] = 0.f;
  __syncthreads();

  {
    const float* __restrict__ VeT = ws + OFF_VET;
    for (int i = tid; i < 16 * 576; i += 512) {
      int t = i & 63, dd = (i >> 6) % 9, m = i / 576;
      float acc = 0.f;
      for (int s = 0; s < 64; ++s) acc += bfu2f(xbL[m * 576 + s * 9 + dd]) * VeT[s * 64 + t];
      aiL[m * 576 + dd * 64 + t] = f2bfu(acc);
    }
  }
  const float ve_r = v_e_g[l];
  const int ig = w * 16 + l15;
  float bbq[4];
  #pragma unroll
  for (int q = 0; q < 4; ++q) bbq[q] = ws[OFF_BENC + q * 128 + ig];
  __syncthreads();

  for (int t = 0; t < S_; ++t) {
    unsigned short* bufC = hA[t & 1];
    unsigned short* bufN = hA[(t + 1) & 1];
    if (w < 4) {
      f32x4 acc = {0.f, 0.f, 0.f, 0.f};
      #pragma unroll
      for (int ks = 0; ks < 8; ++ks) {
        uint4 au = *(const uint4*)&bufC[l15 * 296 + ks * 32 + quad * 8];
        uint4 bu = *(const uint4*)(WeTm + (size_t)((ks * 4 + w) * 64 + l) * 8);
        acc = __builtin_amdgcn_mfma_f32_16x16x32_bf16(
            __builtin_bit_cast(bf16x8, au), __builtin_bit_cast(bf16x8, bu), acc, 0, 0, 0);
      }
      #pragma unroll
      for (int r = 0; r < 4; ++r)
        ahL[(quad * 4 + r) * 64 + w * 16 + l15] = acc[r];
    }
    __syncthreads();
    {
      const int m0 = 2 * w, m1 = 2 * w + 1;
      float a0 = ahL[m0 * 64 + l], a1 = ahL[m1 * 64 + l];
      float e0k = -1e30f, e1k = -1e30f;
      #pragma unroll
      for (int dd = 0; dd < 9; ++dd) {
        float t0 = fast_tanh(a0 + bfu2f(aiL[m0 * 576 + dd * 64 + l])) * ve_r;
        float t1 = fast_tanh(a1 + bfu2f(aiL[m1 * 576 + dd * 64 + l])) * ve_r;
        #pragma unroll
        for (int off = 32; off; off >>= 1) {
          t0 += __shfl_xor(t0, off, 64);
          t1 += __shfl_xor(t1, off, 64);
        }
        if (l == dd) { e0k = t0; e1k = t1; }
      }
      float mx0 = e0k, mx1 = e1k;
      #pragma unroll
      for (int off = 8; off; off >>= 1) {
        mx0 = fmaxf(mx0, __shfl_xor(mx0, off, 64));
        mx1 = fmaxf(mx1, __shfl_xor(mx1, off, 64));
      }
      float ex0 = (l < 9) ? __expf(e0k - mx0) : 0.f;
      float ex1 = (l < 9) ? __expf(e1k - mx1) : 0.f;
      float s0 = ex0, s1 = ex1;
      #pragma unroll
      for (int off = 8; off; off >>= 1) {
        s0 += __shfl_xor(s0, off, 64);
        s1 += __shfl_xor(s1, off, 64);
      }
      if (l < 9) {
        bufC[m0 * 296 + 256 + l] = f2bfu(__fdividef(ex0, s0) * bfu2f(xbL[m0 * 576 + t * 9 + l]));
        bufC[m1 * 296 + 256 + l] = f2bfu(__fdividef(ex1, s1) * bfu2f(xbL[m1 * 576 + t * 9 + l]));
      }
    }
    __syncthreads();
    {
      uint4 af[5];
      #pragma unroll
      for (int ks = 0; ks < 4; ++ks)
        af[ks] = *(const uint4*)&bufC[l15 * 296 + ks * 32 + quad * 8];
      af[4] = *(const uint4*)&bufC[l15 * 296 + 256 + quad * 8];
      f32x4 g4[4];
      #pragma unroll
      for (int q = 0; q < 4; ++q) {
        f32x4 acc = {0.f, 0.f, 0.f, 0.f};
        #pragma unroll
        for (int ks = 0; ks < 5; ++ks) {
          uint4 bu = *(const uint4*)(WencTm + (size_t)(((w * 4 + q) * 5 + ks) * 64 + l) * 8);
          acc = __builtin_amdgcn_mfma_f32_16x16x32_bf16(
              __builtin_bit_cast(bf16x8, af[ks]), __builtin_bit_cast(bf16x8, bu), acc, 0, 0, 0);
        }
        g4[q] = acc;
      }
      #pragma unroll
      for (int r = 0; r < 4; ++r) {
        int m = quad * 4 + r;
        float gi = g4[0][r] + bbq[0];
        float gf = g4[1][r] + bbq[1];
        float gg = g4[2][r] + bbq[2];
        float go = g4[3][r] + bbq[3];
        float co = cF[m * 132 + ig];
        float cn = sigf(gf) * co + sigf(gi) * fast_tanh(gg);
        float hn = sigf(go) * fast_tanh(cn);
        cF[m * 132 + ig] = cn;
        bufN[m * 296 + ig] = f2bfu(hn);
        bufN[m * 296 + 128 + ig] = f2bfu(cn);
        EH[((size_t)(b0 + m) * S_ + t) * H_ + ig] = __float2bfloat16(hn);
      }
    }
    __syncthreads();
  }
  for (int i = tid; i < 16 * 128; i += 512) {
    int m = i >> 7, ii = i & 127;
    dG[(size_t)(b0 + m) * 128 + ii] = hA[0][m * 296 + ii];
    cG[(size_t)(b0 + m) * 128 + ii] = cF[m * 132 + ii];
  }
}

// ---------------------------------------------------------------- attn_encoder^T via MFMA -> fp8
// Emits AETf8 (k-packed, fp8) and EHf8 ([s][i], fp8) for the decoder's streaming phases.
__global__ __launch_bounds__(256) void attnenc_mfma_kernel(
    const unsigned short* __restrict__ EH, const unsigned short* __restrict__ VdTm,
    unsigned char* __restrict__ AETf8, unsigned char* __restrict__ EHf8) {
  const int tid = threadIdx.x;
  const int b = blockIdx.x * 4 + (tid >> 6);
  const int l = tid & 63;
  const int quad = l >> 4, l15 = l & 15;

  const unsigned short* ehb = EH + (size_t)b * 8192;
  uint4 A[4][4];
  #pragma unroll
  for (int st = 0; st < 4; ++st)
    #pragma unroll
    for (int ks = 0; ks < 4; ++ks)
      A[st][ks] = *(const uint4*)(ehb + (st * 16 + l15) * 128 + ks * 32 + quad * 8);

  // EHf8: convert register-resident A-frags
  {
    unsigned char* e8b = EHf8 + (size_t)b * 8192;
    #pragma unroll
    for (int st = 0; st < 4; ++st)
      #pragma unroll
      for (int ks = 0; ks < 4; ++ks) {
        uint4 a = A[st][ks];
        uint2 pk;
        pk.x = pack4_f8(bf_lo(a.x), bf_hi(a.x), bf_lo(a.y), bf_hi(a.y));
        pk.y = pack4_f8(bf_lo(a.z), bf_hi(a.z), bf_lo(a.w), bf_hi(a.w));
        *(uint2*)(e8b + (st * 16 + l15) * 128 + ks * 32 + quad * 8) = pk;
      }
  }

  unsigned char* outb = AETf8 + (size_t)b * 8192;
  const int k = l15;
  #pragma unroll
  for (int nt = 0; nt < 8; ++nt) {
    uint4 Bf[4];
    #pragma unroll
    for (int ks = 0; ks < 4; ++ks)
      Bf[ks] = *(const uint4*)(VdTm + (size_t)((ks * 8 + nt) * 64 + l) * 8);
    int kg = nt * 16 + k;
    int kb = kg >> 3, k7 = kg & 7;
    #pragma unroll
    for (int st = 0; st < 4; ++st) {
      f32x4 acc = {0.f, 0.f, 0.f, 0.f};
      #pragma unroll
      for (int ks = 0; ks < 4; ++ks)
        acc = __builtin_amdgcn_mfma_f32_16x16x32_bf16(
            __builtin_bit_cast(bf16x8, A[st][ks]), __builtin_bit_cast(bf16x8, Bf[ks]), acc, 0, 0, 0);
      #pragma unroll
      for (int r = 0; r < 4; ++r) {
        int s = st * 16 + quad * 4 + r;
        outb[kb * 512 + s * 8 + k7] = f2f8(acc[r]);
      }
    }
  }
}

// ---------------------------------------------------------------- decoder init: pvsG + ad0 (MFMA)
__global__ __launch_bounds__(256) void init_dec_kernel(
    const float* __restrict__ x_in,
    const unsigned short* __restrict__ dG, const float* __restrict__ cG,
    const unsigned short* __restrict__ WdTm,
    const float* __restrict__ smean_g, const float* __restrict__ sstd_g,
    const float* __restrict__ pmean_g,
    unsigned short* __restrict__ adG, float* __restrict__ pvsG) {
  __shared__ unsigned short dcB[16 * 264];
  const int tid = threadIdx.x;
  const int b0 = blockIdx.x * 16;
  const int l = tid & 63, w = tid >> 6;
  const int quad = l >> 4, l15 = l & 15;

  {
    int m = tid >> 4, i0 = (tid & 15) * 8;
    *(uint4*)&dcB[m * 264 + i0] = *(const uint4*)(dG + (size_t)(b0 + m) * 128 + i0);
    float4 c0 = *(const float4*)(cG + (size_t)(b0 + m) * 128 + i0);
    float4 c1 = *(const float4*)(cG + (size_t)(b0 + m) * 128 + i0 + 4);
    uint4 pk;
    pk.x = pack_bf(c0.x, c0.y); pk.y = pack_bf(c0.z, c0.w);
    pk.z = pack_bf(c1.x, c1.y); pk.w = pack_bf(c1.z, c1.w);
    *(uint4*)&dcB[m * 264 + 128 + i0] = pk;
  }
  if (tid < 48) {
    int m = tid / 3, jj = tid % 3;
    const float* xi = x_in + (size_t)(b0 + m) * 576;
    float sm = smean_g[jj], ss = sstd_g[jj], pm = pmean_g[jj];
    float v  = xi[63 * 9 + 3 + jj] * ss + sm;
    float pv = xi[62 * 9 + 3 + jj] * ss + sm;
    float* P = pvsG + (size_t)(b0 + m) * 12;
    P[jj] = xi[63 * 9 + jj] + pm;
    P[3 + jj] = v;
    P[6 + jj] = (v - pv) / DT_;
  }
  __syncthreads();
  #pragma unroll
  for (int t = 0; t < 2; ++t) {
    const int nt = w + 4 * t;
    f32x4 acc = {0.f, 0.f, 0.f, 0.f};
    #pragma unroll
    for (int ks = 0; ks < 8; ++ks) {
      uint4 au = *(const uint4*)&dcB[l15 * 264 + ks * 32 + quad * 8];
      uint4 bu = *(const uint4*)(WdTm + (size_t)((ks * 8 + nt) * 64 + l) * 8);
      acc = __builtin_amdgcn_mfma_f32_16x16x32_bf16(
          __builtin_bit_cast(bf16x8, au), __builtin_bit_cast(bf16x8, bu), acc, 0, 0, 0);
    }
    int n = nt * 16 + l15;
    #pragma unroll
    for (int r = 0; r < 4; ++r)
      adG[(size_t)(b0 + quad * 4 + r) * 128 + n] = f2bfu(acc[r]);
  }
}

// ---------------------------------------------------------------- per-step attention (fp8 streaming)
__global__ __launch_bounds__(256, 8) void attn_step_kernel(
    const unsigned char* __restrict__ AETf8, const unsigned char* __restrict__ EHf8,
    const unsigned short* __restrict__ adG, const float* __restrict__ v_d_g,
    unsigned short* __restrict__ ctxG) {
  __shared__ unsigned short adL[2 * 128];
  __shared__ float vdL[128];
  __shared__ float scp[2][2][64];
  __shared__ float bet[2][64];
  __shared__ float ctxP[2][2][128];

  const int tid = threadIdx.x;
  const int b0 = blockIdx.x * 2;
  const int l = tid & 63, w = tid >> 6;
  const int ml = w >> 1, half = w & 1;
  const int quad = l >> 4, l15 = l & 15;

  if (tid < 32)
    *(uint4*)&adL[tid * 8] = *(const uint4*)(adG + (size_t)(b0 + (tid >> 4)) * 128 + (tid & 15) * 8);
  if (tid < 128) vdL[tid] = v_d_g[tid];
  __syncthreads();

  // scores: lane = s, partial over k-half (fp8 AET stream)
  {
    const unsigned char* aet = AETf8 + (size_t)(b0 + ml) * 8192 + (size_t)half * 8 * 512;
    const unsigned short* adp = adL + ml * 128 + half * 64;
    float e = 0.f;
    #pragma unroll
    for (int kb = 0; kb < 8; ++kb) {
      uint2 av = *(const uint2*)(aet + kb * 512 + l * 8);
      uint4 ad8 = *(const uint4*)(adp + kb * 8);
      float4 v0 = *(const float4*)&vdL[half * 64 + kb * 8];
      float4 v1 = *(const float4*)&vdL[half * 64 + kb * 8 + 4];
      e += fast_tanh(bf_lo(ad8.x) + f8tof(av.x))       * v0.x;
      e += fast_tanh(bf_hi(ad8.x) + f8tof(av.x >> 8))  * v0.y;
      e += fast_tanh(bf_lo(ad8.y) + f8tof(av.x >> 16)) * v0.z;
      e += fast_tanh(bf_hi(ad8.y) + f8tof(av.x >> 24)) * v0.w;
      e += fast_tanh(bf_lo(ad8.z) + f8tof(av.y))       * v1.x;
      e += fast_tanh(bf_hi(ad8.z) + f8tof(av.y >> 8))  * v1.y;
      e += fast_tanh(bf_lo(ad8.w) + f8tof(av.y >> 16)) * v1.z;
      e += fast_tanh(bf_hi(ad8.w) + f8tof(av.y >> 24)) * v1.w;
    }
    scp[ml][half][l] = e;
  }
  __syncthreads();
  if (half == 0) {
    float e = scp[ml][0][l] + scp[ml][1][l];
    float mx = e;
    #pragma unroll
    for (int off = 32; off; off >>= 1) mx = fmaxf(mx, __shfl_xor(mx, off, 64));
    float ex = __expf(e - mx);
    float ss = ex;
    #pragma unroll
    for (int off = 32; off; off >>= 1) ss += __shfl_xor(ss, off, 64);
    bet[ml][l] = __fdividef(ex, ss);
  }
  __syncthreads();
  // context partial over s-half (fp8 EH stream)
  {
    const unsigned char* base = EHf8 + (size_t)(b0 + ml) * 8192 + (size_t)half * 32 * 128;
    float a[8];
    #pragma unroll
    for (int r = 0; r < 8; ++r) a[r] = 0.f;
    #pragma unroll
    for (int it = 0; it < 8; ++it) {
      int sl = it * 4 + quad;
      uint2 ev = *(const uint2*)(base + sl * 128 + l15 * 8);
      float bt = bet[ml][half * 32 + sl];
      a[0] += bt * f8tof(ev.x);       a[1] += bt * f8tof(ev.x >> 8);
      a[2] += bt * f8tof(ev.x >> 16); a[3] += bt * f8tof(ev.x >> 24);
      a[4] += bt * f8tof(ev.y);       a[5] += bt * f8tof(ev.y >> 8);
      a[6] += bt * f8tof(ev.y >> 16); a[7] += bt * f8tof(ev.y >> 24);
    }
    #pragma unroll
    for (int r = 0; r < 8; ++r) {
      a[r] += __shfl_xor(a[r], 16, 64);
      a[r] += __shfl_xor(a[r], 32, 64);
    }
    if (quad == 0) {
      *(float4*)&ctxP[ml][half][l15 * 8]     = make_float4(a[0], a[1], a[2], a[3]);
      *(float4*)&ctxP[ml][half][l15 * 8 + 4] = make_float4(a[4], a[5], a[6], a[7]);
    }
  }
  __syncthreads();
  if (tid < 128) {
    int mi = tid >> 6, hp = (tid & 63) * 2;
    float c0 = ctxP[mi][0][hp]     + ctxP[mi][1][hp];
    float c1 = ctxP[mi][0][hp + 1] + ctxP[mi][1][hp + 1];
    *(unsigned int*)(ctxG + (size_t)(b0 + mi) * 128 + hp) = pack_bf(c0, c1);
  }
}

// ---------------------------------------------------------------- per-step GEMM: gates+LSTM+out+next ad
__global__ __launch_bounds__(512, 2) void gemm_step_kernel(
    const float* __restrict__ ws,
    const unsigned short* __restrict__ dG_in, float* __restrict__ cG,
    const unsigned short* __restrict__ ctxG,
    const unsigned short* __restrict__ WdTm, const unsigned short* __restrict__ WdecTm,
    unsigned short* __restrict__ dG_out, unsigned short* __restrict__ adG,
    float* __restrict__ pvsG,
    const float* __restrict__ b_out_g, const float* __restrict__ smean_g,
    const float* __restrict__ sstd_g, const float* __restrict__ pmean_g,
    float* __restrict__ out, int hz) {
  __shared__ unsigned short gA[16 * 296];
  __shared__ unsigned short dcB[16 * 264];
  __shared__ float pd[16 * 3 * 8];
  __shared__ float pc[16 * 3 * 4];

  const int tid = threadIdx.x;
  const int b0 = blockIdx.x * 16;
  const int l = tid & 63, w = tid >> 6;
  const int quad = l >> 4, l15 = l & 15;

  if (tid < 256) {
    int m = tid >> 4, i0 = (tid & 15) * 8;
    *(uint4*)&gA[m * 296 + i0] = *(const uint4*)(dG_in + (size_t)(b0 + m) * 128 + i0);
  } else {
    int t = tid - 256;
    int m = t >> 4, i0 = (t & 15) * 8;
    *(uint4*)&gA[m * 296 + 128 + i0] = *(const uint4*)(ctxG + (size_t)(b0 + m) * 128 + i0);
  }
  if (tid < 496) { int mm = tid / 31, r = tid % 31; gA[mm * 296 + 265 + r] = 0; }
  if (tid < 48) {
    int m = tid / 3, jj = tid % 3;
    const float* P = pvsG + (size_t)(b0 + m) * 12;
    float sm = smean_g[jj], ss = sstd_g[jj], pm = pmean_g[jj];
    gA[m * 296 + 256 + jj]     = f2bfu(P[jj] - pm);
    gA[m * 296 + 256 + 3 + jj] = f2bfu((P[3 + jj] - sm) / ss);
    gA[m * 296 + 256 + 6 + jj] = f2bfu(P[6 + jj] / ss);
  }
  __syncthreads();

  {
    uint4 af[9];
    #pragma unroll
    for (int ks = 0; ks < 9; ++ks)
      af[ks] = *(const uint4*)&gA[l15 * 296 + ks * 32 + quad * 8];
    const int is = w, i = is * 16 + l15;
    float bb[4], wd[3];
    #pragma unroll
    for (int q = 0; q < 4; ++q) bb[q] = ws[OFF_BDEC + q * 128 + i];
    #pragma unroll
    for (int jj = 0; jj < 3; ++jj) wd[jj] = ws[OFF_WOUTT + i * 3 + jj];
    f32x4 g4[4];
    #pragma unroll
    for (int q = 0; q < 4; ++q) {
      f32x4 acc = {0.f, 0.f, 0.f, 0.f};
      #pragma unroll
      for (int ks = 0; ks < 9; ++ks) {
        uint4 bu = *(const uint4*)(WdecTm + (size_t)(((is * 4 + q) * 9 + ks) * 64 + l) * 8);
        acc = __builtin_amdgcn_mfma_f32_16x16x32_bf16(
            __builtin_bit_cast(bf16x8, af[ks]), __builtin_bit_cast(bf16x8, bu), acc, 0, 0, 0);
      }
      g4[q] = acc;
    }
    float pr[4][3];
    #pragma unroll
    for (int r = 0; r < 4; ++r) {
      int m = quad * 4 + r;
      float gi = g4[0][r] + bb[0];
      float gf = g4[1][r] + bb[1];
      float gg = g4[2][r] + bb[2];
      float go = g4[3][r] + bb[3];
      float co = cG[(size_t)(b0 + m) * 128 + i];
      float cn = sigf(gf) * co + sigf(gi) * fast_tanh(gg);
      float hn = sigf(go) * fast_tanh(cn);
      cG[(size_t)(b0 + m) * 128 + i] = cn;
      unsigned short hb = f2bfu(hn);
      dG_out[(size_t)(b0 + m) * 128 + i] = hb;
      dcB[m * 264 + i] = hb;
      dcB[m * 264 + 128 + i] = f2bfu(cn);
      pr[r][0] = hn * wd[0]; pr[r][1] = hn * wd[1]; pr[r][2] = hn * wd[2];
    }
    #pragma unroll
    for (int r = 0; r < 4; ++r)
      #pragma unroll
      for (int jj = 0; jj < 3; ++jj) {
        float v = pr[r][jj];
        #pragma unroll
        for (int off = 8; off; off >>= 1) v += __shfl_xor(v, off, 64);
        pr[r][jj] = v;
      }
    if (l15 == 0) {
      #pragma unroll
      for (int r = 0; r < 4; ++r)
        #pragma unroll
        for (int jj = 0; jj < 3; ++jj)
          pd[((quad * 4 + r) * 3 + jj) * 8 + is] = pr[r][jj];
    }
  }
  __syncthreads();

  {
    const int nt = w;
    f32x4 acc = {0.f, 0.f, 0.f, 0.f};
    #pragma unroll
    for (int ks = 0; ks < 8; ++ks) {
      uint4 au = *(const uint4*)&dcB[l15 * 264 + ks * 32 + quad * 8];
      uint4 bu = *(const uint4*)(WdTm + (size_t)((ks * 8 + nt) * 64 + l) * 8);
      acc = __builtin_amdgcn_mfma_f32_16x16x32_bf16(
          __builtin_bit_cast(bf16x8, au), __builtin_bit_cast(bf16x8, bu), acc, 0, 0, 0);
    }
    int n = nt * 16 + l15;
    #pragma unroll
    for (int r = 0; r < 4; ++r) {
      int m = quad * 4 + r;
      adG[(size_t)(b0 + m) * 128 + n] = f2bfu(acc[r]);
    }
  }
  if (tid < 192) {
    int m = tid / 12, jj = (tid % 12) / 4, part = tid % 4;
    int k0 = part * 32;
    float acc = 0.f;
    for (int k = k0; k < k0 + 32; ++k) {
      __hip_bfloat16 hv = *(__hip_bfloat16*)&gA[m * 296 + 128 + k];
      acc += __bfloat162float(hv) * ws[OFF_WOUTT + 384 + k * 3 + jj];
    }
    pc[(m * 3 + jj) * 4 + part] = acc;
  }
  __syncthreads();

  if (tid < 48) {
    int m = tid / 3, jj = tid % 3;
    float s = b_out_g[jj];
    #pragma unroll
    for (int p = 0; p < 4; ++p) s += pc[(m * 3 + jj) * 4 + p];
    #pragma unroll
    for (int is = 0; is < 8; ++is) s += pd[(m * 3 + jj) * 8 + is];
    float pacc = s * sstd_g[jj];
    float* P = pvsG + (size_t)(b0 + m) * 12;
    float pos = P[jj], vel = P[3 + jj], acc = P[6 + jj];
    float ppred = pos + vel * DT_ + 0.5f * acc * DT_ * DT_;
    float vnew  = vel + 0.5f * (acc + pacc) * DT_;
    size_t ob = ((size_t)(b0 + m) * HZ_ + hz) * 9;
    out[ob + jj] = ppred; out[ob + 3 + jj] = vnew; out[ob + 6 + jj] = pacc;
    P[jj] = ppred; P[3 + jj] = vnew; P[6 + jj] = pacc;
  }
}

// ---------------------------------------------------------------- launch
extern "C" void kernel_launch(void* const* d_in, const int* in_sizes, int n_in,
                              void* d_out, int out_size, void* d_ws, size_t ws_size,
                              hipStream_t stream) {
  (void)in_sizes; (void)n_in; (void)out_size; (void)ws_size;
  const float* x      = (const float*)d_in[0];
  const float* Wih_e  = (const float*)d_in[1];
  const float* Whh_e  = (const float*)d_in[2];
  const float* bih_e  = (const float*)d_in[3];
  const float* bhh_e  = (const float*)d_in[4];
  const float* W_e    = (const float*)d_in[5];
  const float* V_e    = (const float*)d_in[6];
  const float* v_e    = (const float*)d_in[7];
  const float* W_d    = (const float*)d_in[8];
  const float* V_d    = (const float*)d_in[9];
  const float* v_d    = (const float*)d_in[10];
  const float* Wih_d  = (const float*)d_in[11];
  const float* Whh_d  = (const float*)d_in[12];
  const float* bih_d  = (const float*)d_in[13];
  const float* bhh_d  = (const float*)d_in[14];
  const float* W_out  = (const float*)d_in[15];
  const float* b_out  = (const float*)d_in[16];
  const float* smean  = (const float*)d_in[17];
  const float* sstd   = (const float*)d_in[18];
  const float* pmean  = (const float*)d_in[19];

  float* ws = (float*)d_ws;
  float* pvsG = ws;                                           // over dead encoder tables
  unsigned short* WeTm   = (unsigned short*)(ws + OFF_WET);
  unsigned short* WencTm = (unsigned short*)(ws + OFF_WENCT);
  unsigned short* WdTm   = (unsigned short*)(ws + OFF_WDT);
  unsigned short* WdecTm = (unsigned short*)(ws + OFF_WDECT);
  unsigned short* VdTm   = (unsigned short*)(ws + OFF_VDT);
  unsigned short* dG     = (unsigned short*)(ws + OFF_DECD);
  unsigned short* ctxG   = dG + 524288;
  float* cG = ws + OFF_DECC;
  unsigned short* ub  = (unsigned short*)(ws + F32_TOTAL);
  unsigned short* EH  = ub;
  unsigned char*  AETf8 = (unsigned char*)(ub + 33554432);     // 33.5 MB
  unsigned char*  EHf8  = AETf8 + (size_t)B_ * 8192;           // 33.5 MB (fills old AET slot)
  unsigned short* adG = ub + 67108864;
  float* out = (float*)d_out;

  prep_kernel<<<(PREP_N + 255) / 256, 256, 0, stream>>>(
      Wih_e, Whh_e, bih_e, bhh_e, W_e, V_e, W_d, V_d,
      Wih_d, Whh_d, bih_d, bhh_d, W_out, ws);
  prep_mfma_kernel<<<(32768 + 147456 + 255) / 256, 256, 0, stream>>>(
      W_d, Wih_d, Whh_d, WdTm, WdecTm);
  prep_enc_mfma_kernel<<<(16384 + 81920 + 16384 + 255) / 256, 256, 0, stream>>>(
      W_e, Wih_e, Whh_e, V_d, WeTm, WencTm, VdTm);
  encoder_mfma_kernel<<<B_ / 16, 512, 0, stream>>>(
      x, ws, v_e, WeTm, WencTm, (__hip_bfloat16*)EH, dG, cG);
  attnenc_mfma_kernel<<<B_ / 4, 256, 0, stream>>>(EH, VdTm, AETf8, EHf8);
  init_dec_kernel<<<B_ / 16, 256, 0, stream>>>(
      x, dG, cG, WdTm, smean, sstd, pmean, adG, pvsG);
  for (int hz = 0; hz < HZ_; ++hz) {
    attn_step_kernel<<<B_ / 2, 256, 0, stream>>>(AETf8, EHf8, adG, v_d, ctxG);
    gemm_step_kernel<<<B_ / 16, 512, 0, stream>>>(
        ws, dG, cG, ctxG, WdTm, WdecTm, dG, adG, pvsG,
        b_out, smean, sstd, pmean, out, hz);
  }
}